// Round 14
// baseline (910.577 us; speedup 1.0000x reference)
//
#include <hip/hip_runtime.h>
#include <hip/hip_bf16.h>
#include <math.h>

// Shapes: B=8, N=64, P=256, DIM=128, HEADS=8, DK=16, HID=512
#define INV_SCALE 3.3635856610148585f  // 128**0.25

typedef float f32x4 __attribute__((ext_vector_type(4)));
typedef short bf16x8 __attribute__((ext_vector_type(8)));
typedef unsigned short u16;
#define MFMA(a_, b_, c_) __builtin_amdgcn_mfma_f32_16x16x32_bf16(a_, b_, c_, 0, 0, 0)

// ---------------- ws layout (float offsets) ----------------
// Fragment layouts: frag[q][kk][lane(64)][8] with lane=lk*16+lr holding M[q*16+lr][kk*32+lk*8+e].
constexpr int WT_ATT = 0;                 // 5 * 16384 (slots 1,3 = bf16 hi/lo FRAGMENT layout)
constexpr int WT_DEC = 81920;             // 8 * 16384
constexpr int WT_M1  = 212992;            // 2 * 65536 (bf16 RNE fragment [32q][4kk], lo slot unused)
constexpr int WT_M2  = 344064;            // 2 * 65536 (bf16 RNE fragment [8q][16kk], lo slot unused)
constexpr int O_PX   = 475136;            // 8*256*128
constexpr int O_MX   = 737280;            // 8*64*128
constexpr int O_MA   = 802816;            // 8*64*64*128
constexpr int O_QL   = 4997120;           // 8*256*128
constexpr int O_VL   = 5259264;
constexpr int O_QXL  = 5521408;
constexpr int O_VXL  = 5586944;
constexpr int O_KXL  = 5652480;
constexpr int O_PX1  = 5914624;
constexpr int O_MX1  = 6176768;
constexpr int O_S    = 6242304;           // 8*8*256*256
constexpr int O_MSG  = 10469376;          // free region: col partial max/sum live here
constexpr int O_NH   = 14663680;          // 8*8*256*16
constexpr int O_RS   = 14925824;          // 8*8*128
constexpr int O_KS   = 14934016;          // 8*8*16
constexpr int O_SE   = 14935040;          // 8*8*64*64
constexpr int O_ME2  = 15197184;
constexpr int O_VAS  = 15459328;          // 8*8*64*16
constexpr int O_MROW = 15524864;          // 8*8*64
constexpr int O_S2   = 15528960;          // (unused now)
constexpr int O_MA1  = 16577536;          // 8*64*64*128 ; BEFORE ma1: msg bf16 hi/lo FRAGMENT layout
// total = 20771840 floats (~79 MB, proven)

constexpr int OUT1_OFF = 4194304;         // node_hidden
constexpr int OUT2_OFF = 4259840;         // attn_dec

__device__ __forceinline__ float waveSum(float v) {
#pragma unroll
  for (int o = 32; o > 0; o >>= 1) v += __shfl_down(v, o, 64);
  return v;
}

__device__ __forceinline__ void split1(float a, u16& h, u16& l) {
  unsigned ua = __float_as_uint(a) & 0xffff0000u;
  h = (u16)(ua >> 16);
  float al = a - __uint_as_float(ua);
  l = (u16)(__float_as_uint(al) >> 16);
}
__device__ __forceinline__ void split8(const float* p, bf16x8& hi, bf16x8& lo) {
#pragma unroll
  for (int i = 0; i < 8; i++) {
    float a = p[i];
    unsigned ua = __float_as_uint(a) & 0xffff0000u;
    float al = a - __uint_as_float(ua);
    hi[i] = (short)(u16)(ua >> 16);
    lo[i] = (short)(u16)(__float_as_uint(al) >> 16);
  }
}
__device__ __forceinline__ u16 rne1(float a) {
  unsigned u = __float_as_uint(a);
  u += 0x7fffu + ((u >> 16) & 1u);
  return (u16)(u >> 16);
}
__device__ __forceinline__ bf16x8 rne8(const float* p) {
  bf16x8 h;
#pragma unroll
  for (int i = 0; i < 8; i++) h[i] = (short)rne1(p[i]);
  return h;
}

// ---------------- weight prep (fragment layouts for MFMA-consumed weights) ----------------
__global__ __launch_bounds__(256) void prep_wt(
    const float* __restrict__ att_w, const float* __restrict__ dec_w,
    const float* __restrict__ mlp_w1, const float* __restrict__ mlp_w2,
    float* __restrict__ ws) {
  int seg = blockIdx.x, t = threadIdx.x;
  if (seg < 5) {
    const float* w = att_w + seg * 16384;
    if (seg == 1 || seg == 3) {   // fragment layout [8q][4kk][64lane][8e], hi; lo at +16384 (3-term split)
      u16* oh = (u16*)(ws + WT_ATT + seg * 16384);
      for (int idx = t; idx < 16384; idx += 256) {
        int e = idx & 7, lane = (idx >> 3) & 63, kk = (idx >> 9) & 3, q = idx >> 11;
        int o = q * 16 + (lane & 15), i = kk * 32 + (lane >> 4) * 8 + e;
        u16 hh, ll; split1(w[o * 128 + i], hh, ll);
        oh[idx] = hh; oh[16384 + idx] = ll;
      }
    } else {
      float* o = ws + WT_ATT + seg * 16384;
      for (int idx = t; idx < 16384; idx += 256) o[idx] = w[(idx & 127) * 128 + (idx >> 7)];
    }
  } else if (seg < 13) {
    int k = seg - 5;
    const float* w = dec_w + k * 16384;
    float* o = ws + WT_DEC + k * 16384;
    for (int idx = t; idx < 16384; idx += 256) o[idx] = w[(idx & 127) * 128 + (idx >> 7)];
  } else if (seg < 15) {
    int k = seg - 13;
    const float* w = mlp_w1 + k * 65536;   // [512][128] -> fragment [32q][4kk][64][8], RNE bf16
    u16* oh = (u16*)(ws + WT_M1 + k * 65536);
    for (int idx = t; idx < 65536; idx += 256) {
      int e = idx & 7, lane = (idx >> 3) & 63, kk = (idx >> 9) & 3, q = idx >> 11;
      int o = q * 16 + (lane & 15), i = kk * 32 + (lane >> 4) * 8 + e;
      oh[idx] = rne1(w[o * 128 + i]); oh[65536 + idx] = 0;
    }
  } else {
    int k = seg - 15;
    const float* w = mlp_w2 + k * 65536;   // [128][512] -> fragment [8q][16kk][64][8], RNE bf16
    u16* oh = (u16*)(ws + WT_M2 + k * 65536);
    for (int idx = t; idx < 65536; idx += 256) {
      int e = idx & 7, lane = (idx >> 3) & 63, kk = (idx >> 9) & 15, q = idx >> 13;
      int o = q * 16 + (lane & 15), i = kk * 32 + (lane >> 4) * 8 + e;
      oh[idx] = rne1(w[o * 512 + i]); oh[65536 + idx] = 0;
    }
  }
}

// ---------------- vectorized LayerNorm: 4 rows per 128-thread block, float4 lanes ----------------
__global__ __launch_bounds__(128) void ln_rows4(const float* __restrict__ in, float* __restrict__ out,
                                                const float* __restrict__ g, const float* __restrict__ b) {
  int t = threadIdx.x;
  size_t row = (size_t)blockIdx.x * 4 + (t >> 5);
  int c4 = (t & 31) * 4;
  float4 x = *(const float4*)&in[row * 128 + c4];
  float s = x.x + x.y + x.z + x.w;
#pragma unroll
  for (int o = 16; o > 0; o >>= 1) s += __shfl_xor(s, o, 64);
  float mean = s * (1.f / 128.f);
  float dx = x.x - mean, dy = x.y - mean, dz = x.z - mean, dw = x.w - mean;
  float v = dx * dx + dy * dy + dz * dz + dw * dw;
#pragma unroll
  for (int o = 16; o > 0; o >>= 1) v += __shfl_xor(v, o, 64);
  float rstd = rsqrtf(v * (1.f / 128.f) + 1e-5f);
  float4 gv = *(const float4*)&g[c4];
  float4 bv = *(const float4*)&b[c4];
  float4 o4;
  o4.x = dx * rstd * gv.x + bv.x;
  o4.y = dy * rstd * gv.y + bv.y;
  o4.z = dz * rstd * gv.z + bv.z;
  o4.w = dw * rstd * gv.w + bv.w;
  *(float4*)&out[row * 128 + c4] = o4;
}

// ---------------- dual small linear ----------------
__global__ __launch_bounds__(128) void lin_rows2(const float* __restrict__ in,
                                                 float* __restrict__ out1, const float* __restrict__ WT1,
                                                 const float* __restrict__ b1v,
                                                 float* __restrict__ out2, const float* __restrict__ WT2,
                                                 const float* __restrict__ b2v) {
  int row = blockIdx.x, t = threadIdx.x;
  __shared__ float rl[128];
  rl[t] = in[(size_t)row * 128 + t];
  __syncthreads();
  float a1 = b1v[t], a2 = b2v[t];
#pragma unroll 8
  for (int i = 0; i < 128; i++) {
    float rv = rl[i];
    a1 += rv * WT1[i * 128 + t];
    a2 += rv * WT2[i * 128 + t];
  }
  out1[(size_t)row * 128 + t] = a1;
  out2[(size_t)row * 128 + t] = a2;
}

// ---------------- shared LN-over-32-rows helper (256 threads) ----------------
__device__ __forceinline__ void ln32_stats(float (*tile)[132], float* psum, float* meanL, float* rstdL,
                                           int t) {
  int r = t >> 3, seg = t & 7;
  float p = 0;
#pragma unroll
  for (int k = 0; k < 16; k++) p += tile[r][seg * 16 + k];
  psum[r * 8 + seg] = p;
  __syncthreads();
  if (t < 32) { float sm = 0; for (int k = 0; k < 8; k++) sm += psum[t * 8 + k]; meanL[t] = sm * (1.f / 128.f); }
  __syncthreads();
  float mu = meanL[r];
  p = 0;
#pragma unroll
  for (int k = 0; k < 16; k++) { float d = tile[r][seg * 16 + k] - mu; p += d * d; }
  psum[r * 8 + seg] = p;
  __syncthreads();
  if (t < 32) { float sm = 0; for (int k = 0; k < 8; k++) sm += psum[t * 8 + k]; rstdL[t] = rsqrtf(sm * (1.f / 128.f) + 1e-5f); }
  __syncthreads();
}

// ---------------- LN-over-32-rows helper (512 threads, 16 thr/row x 8 elems) ----------------
__device__ __forceinline__ void ln32b_stats(float (*tile)[132], float* psum, float* meanL, float* rstdL,
                                            int t) {
  int r = t >> 4, seg = t & 15;
  float p = 0;
#pragma unroll
  for (int k = 0; k < 8; k++) p += tile[r][seg * 8 + k];
  psum[r * 16 + seg] = p;
  __syncthreads();
  if (t < 32) { float sm = 0; for (int k = 0; k < 16; k++) sm += psum[t * 16 + k]; meanL[t] = sm * (1.f / 128.f); }
  __syncthreads();
  float mu = meanL[r];
  p = 0;
#pragma unroll
  for (int k = 0; k < 8; k++) { float d = tile[r][seg * 8 + k] - mu; p += d * d; }
  psum[r * 16 + seg] = p;
  __syncthreads();
  if (t < 32) { float sm = 0; for (int k = 0; k < 16; k++) sm += psum[t * 16 + k]; rstdL[t] = rsqrtf(sm * (1.f / 128.f) + 1e-5f); }
  __syncthreads();
}

// ---------------- K1 (q-folded VALU): s[b,h,m,n] = INV * (paLN @ Wq'^T + bq') ----------------
__global__ __launch_bounds__(256, 8) void k1_fold(
    const float* __restrict__ prot_adj, const float* __restrict__ q_lin,
    const float* __restrict__ wk_orig,  // att_w slot 1, [o=128][i=128] f32
    const float* __restrict__ bk,
    const float* __restrict__ g1, const float* __restrict__ b1,
    float* __restrict__ sdst) {
  __shared__ __align__(16) float paF[32][132];
  __shared__ float wq[8][132];
  __shared__ float qL[16];
  __shared__ float psum[256];
  __shared__ float meanL[32], rstdL[32];
  int t = threadIdx.x, bid = blockIdx.x;
  int b = bid >> 11, h = (bid >> 8) & 7, ai = bid & 255;
  int irow = h * 32 + (ai >> 3), j0 = (ai & 7) * 32;
  int mq = (ai >> 3) * 8 + (ai & 7);
  size_t pabase = (((size_t)(b * 256) + irow) * 256 + j0) * 128;
  {
    const float4* src4 = (const float4*)(prot_adj + pabase);
    for (int idx = t; idx < 1024; idx += 256)
      *(float4*)&paF[idx >> 5][(idx & 31) * 4] = src4[idx];
  }
  if (t < 16) qL[t] = q_lin[((size_t)(b * 256) + h * 32 + (mq >> 3)) * 128 + (mq & 7) * 16 + t];
  __syncthreads();
#pragma unroll
  for (int k = 0; k < 4; k++) {
    int o = t + k * 256;
    int g8 = o >> 7, c = o & 127;
    float s = 0;
#pragma unroll
    for (int d = 0; d < 16; d++) s += qL[d] * wk_orig[(g8 * 16 + d) * 128 + c];
    wq[g8][c] = s;
  }
  ln32_stats(paF, psum, meanL, rstdL, t);
  for (int idx = t; idx < 4096; idx += 256) {
    int r = idx >> 7, c = idx & 127;
    paF[r][c] = (paF[r][c] - meanL[r]) * rstdL[r] * g1[c] + b1[c];
  }
  __syncthreads();
  int r = t >> 3, g8 = t & 7;
  float acc = 0;
#pragma unroll
  for (int d = 0; d < 16; d++) acc += qL[d] * bk[g8 * 16 + d];
#pragma unroll 8
  for (int c = 0; c < 128; c++) acc += paF[r][c] * wq[g8][c];
  size_t sb = ((size_t)((b * 8 + h) * 256 + mq)) * 256;
  sdst[sb + t] = INV_SCALE * acc;
}

// ---------------- column partial stats of s ----------------
__global__ __launch_bounds__(256) void col_part(const float* __restrict__ s, float* __restrict__ pmax,
                                                float* __restrict__ psumv) {
  int bid = blockIdx.x, t = threadIdx.x;
  int bh = bid >> 3, ch = bid & 7;
  const float* sp = s + ((size_t)(bh * 256) + ch * 32) * 256 + t;
  float rm = -3.4e38f, rs = 0.f;
  for (int r = 0; r < 32; r++) {
    float x = sp[(size_t)r * 256];
    float nm = fmaxf(rm, x);
    rs = rs * __expf(rm - nm) + __expf(x - nm);
    rm = nm;
  }
  pmax[(bh * 8 + ch) * 256 + t] = rm;
  psumv[(bh * 8 + ch) * 256 + t] = rs;
}

// ---------------- message tiles: softmaxes + diag; write bf16 hi/lo FRAGMENTS; fused nh MFMA ----------------
__global__ __launch_bounds__(256, 1) void msg_tiles(const float* __restrict__ s,
                                                    const float* __restrict__ pmax, const float* __restrict__ psumv,
                                                    const float* __restrict__ v_lin,
                                                    u16* __restrict__ mhi, u16* __restrict__ mlo,
                                                    float* __restrict__ nh) {
  __shared__ __align__(16) float rowT[32][260];
  __shared__ float sT[256][33];
  __shared__ __align__(16) u16 vTh[16][264];
  __shared__ __align__(16) u16 vTl[16][264];
  __shared__ float red[256];
  __shared__ float rmax[32], rsinv[32], cmaxL[32], csinvL[32];
  int bid = blockIdx.x, t = threadIdx.x;
  int bh = bid >> 3, m0 = (bid & 7) * 32;
  int b = bh >> 3, h = bh & 7;
  size_t sbase = (size_t)(bh * 256) * 256;
  for (int idx = t; idx < 2048; idx += 256) {
    int r = idx >> 6, c4 = (idx & 63) * 4;
    *(float4*)&rowT[r][c4] = *(const float4*)&s[sbase + (size_t)(m0 + r) * 256 + c4];
  }
  for (int idx = t; idx < 2048; idx += 256) {
    int n = idx >> 3, mc4 = (idx & 7) * 4;
    float4 v4 = *(const float4*)&s[sbase + (size_t)n * 256 + m0 + mc4];
    sT[n][mc4] = v4.x; sT[n][mc4 + 1] = v4.y; sT[n][mc4 + 2] = v4.z; sT[n][mc4 + 3] = v4.w;
  }
  {
    const float4* vb4 = (const float4*)(v_lin + ((size_t)(b * 256) + h * 32) * 128);
    for (int idx = t; idx < 1024; idx += 256) {
      float4 v4 = vb4[idx];
#pragma unroll
      for (int i = 0; i < 4; i++) {
        int flat = idx * 4 + i;
        int d = flat & 15, n = flat >> 4;
        u16 hh2, ll2; split1(((const float*)&v4)[i], hh2, ll2);
        vTh[d][n] = hh2; vTl[d][n] = ll2;
      }
    }
  }
  __syncthreads();
  {
    int r = t >> 3, sg = t & 7;
    float pm = -3.4e38f;
    for (int k = 0; k < 32; k++) pm = fmaxf(pm, rowT[r][sg * 32 + k]);
    red[t] = pm;
    __syncthreads();
    if (t < 32) { float mm = red[t * 8]; for (int k = 1; k < 8; k++) mm = fmaxf(mm, red[t * 8 + k]); rmax[t] = mm; }
    __syncthreads();
    float mm = rmax[r], ps = 0;
    for (int k = 0; k < 32; k++) ps += __expf(rowT[r][sg * 32 + k] - mm);
    red[t] = ps;
    __syncthreads();
    if (t < 32) { float sm = 0; for (int k = 0; k < 8; k++) sm += red[t * 8 + k]; rsinv[t] = 1.f / sm; }
    if (t >= 64 && t < 96) {
      int mc = t - 64, col = m0 + mc;
      float cm = -3.4e38f;
      for (int c2 = 0; c2 < 8; c2++) cm = fmaxf(cm, pmax[(bh * 8 + c2) * 256 + col]);
      float cs = 0;
      for (int c2 = 0; c2 < 8; c2++) cs += psumv[(bh * 8 + c2) * 256 + col] * __expf(pmax[(bh * 8 + c2) * 256 + col] - cm);
      cmaxL[mc] = cm; csinvL[mc] = 1.f / cs;
    }
    __syncthreads();
  }
  for (int idx = t; idx < 8192; idx += 256) {
    int r = idx >> 8, n = idx & 255;
    float x = rowT[r][n];
    float outv = __expf(x - rmax[r]) * rsinv[r];
    float inval = __expf(sT[n][r] - cmaxL[r]) * csinvL[r];
    rowT[r][n] = (n == m0 + r) ? inval : (outv + inval);
  }
  __syncthreads();
  // fragment store: frag (bh, mtile, kk, lane) ; lane = lk*16+lr holds msg[mtile*16+lr][kk*32+lk*8+e]
  for (int fi = t; fi < 1024; fi += 256) {
    int r = fi >> 5, fc = fi & 31;
    int m = m0 + r;
    int lane = (fc & 3) * 16 + (m & 15);
    size_t base = (size_t)bh * 65536 + (size_t)(m >> 4) * 4096 + (size_t)(fc >> 2) * 512 + lane * 8;
    bf16x8 h8, l8;
    split8(&rowT[r][fc * 8], h8, l8);
    *(bf16x8*)&mhi[base] = h8;
    *(bf16x8*)&mlo[base] = l8;
  }
  // fused nh = msg_tile @ v : [32m x 16d x 256n], waves 0-1 (reads rowT only)
  int w = t >> 6, l = t & 63, lr = l & 15, lk = l >> 4;
  if (w < 2) {
    f32x4 acc = (f32x4){0.f, 0.f, 0.f, 0.f};
#pragma unroll
    for (int kk = 0; kk < 8; kk++) {
      bf16x8 ah, al;
      split8(&rowT[w * 16 + lr][kk * 32 + lk * 8], ah, al);
      bf16x8 bhv = *(const bf16x8*)&vTh[lr][kk * 32 + lk * 8];
      bf16x8 blv = *(const bf16x8*)&vTl[lr][kk * 32 + lk * 8];
      acc = MFMA(ah, bhv, acc);
      acc = MFMA(al, bhv, acc);
      acc = MFMA(ah, blv, acc);
    }
#pragma unroll
    for (int j = 0; j < 4; j++)
      nh[((size_t)(bh * 256) + m0 + w * 16 + lk * 4 + j) * 16 + lr] = acc[j];
  }
}

// ---------------- fused px1 = LN(px + Lin(nh)) -> kxl = Lin(px1)  (px1 never materialized) ----------------
__global__ __launch_bounds__(128) void px1k_kernel(const float* __restrict__ px, const float* __restrict__ nh,
                                                   const float* __restrict__ WTo, const float* __restrict__ bo,
                                                   const float* __restrict__ g, const float* __restrict__ bt,
                                                   const float* __restrict__ WTk, const float* __restrict__ bkx,
                                                   float* __restrict__ kxl) {
  int p = blockIdx.x, t = threadIdx.x;
  int b = p >> 8, pl = p & 255, h = pl >> 5;
  __shared__ float nodeL[128];
  __shared__ float px1L[128];
  __shared__ float scr[2];
  nodeL[t] = nh[((size_t)(b * 8 + h) * 256 + ((pl & 31) * 8 + (t >> 4))) * 16 + (t & 15)];
  __syncthreads();
  float acc = bo[t];
#pragma unroll 8
  for (int i = 0; i < 128; i++) acc += nodeL[i] * WTo[i * 128 + t];
  float val = px[(size_t)p * 128 + t] + acc;
  float v = waveSum(val);
  if ((t & 63) == 0) scr[t >> 6] = v;
  __syncthreads();
  float mean = (scr[0] + scr[1]) * (1.f / 128.f);
  __syncthreads();
  float dd = val - mean;
  v = waveSum(dd * dd);
  if ((t & 63) == 0) scr[t >> 6] = v;
  __syncthreads();
  float rstd = rsqrtf((scr[0] + scr[1]) * (1.f / 128.f) + 1e-5f);
  px1L[t] = dd * rstd * g[t] + bt[t];
  __syncthreads();
  float a2 = bkx[t];
#pragma unroll 8
  for (int i = 0; i < 128; i++) a2 += px1L[i] * WTk[i * 128 + t];
  kxl[(size_t)p * 128 + t] = a2;
}

// ---------------- fused s2 + message2 + msgrow (512 threads) ----------------
__global__ __launch_bounds__(512, 1) void s2_fused(const float* __restrict__ qxl, const float* __restrict__ kxl,
                                                   float* __restrict__ out2, float* __restrict__ mrow) {
  __shared__ float kxL[256 * 17];
  __shared__ float qxL[64 * 17];
  __shared__ float sL[64][257];
  __shared__ float rmaxL[64], rsinv[64];
  __shared__ float cmaxL[256], csinv[256];
  int bh = blockIdx.x, t = threadIdx.x;
  int b = bh >> 3, h = bh & 7;
  for (int idx = t; idx < 4096; idx += 512) {
    int pl = idx >> 7, cc = idx & 127;
    kxL[(pl * 8 + (cc >> 4)) * 17 + (cc & 15)] = kxl[((size_t)(b * 256) + h * 32 + pl) * 128 + cc];
  }
  for (int idx = t; idx < 1024; idx += 512) {
    int rl = idx >> 7, cc = idx & 127;
    qxL[(rl * 8 + (cc >> 4)) * 17 + (cc & 15)] = qxl[((size_t)(b * 64) + h * 8 + rl) * 128 + cc];
  }
  __syncthreads();
  {
    int p = t & 255, mh = t >> 8;   // 2 threads per column, 32 rows each
    float kr[16];
#pragma unroll
    for (int d = 0; d < 16; d++) kr[d] = kxL[p * 17 + d];
    for (int m = mh * 32; m < mh * 32 + 32; m++) {
      float dot = 0;
#pragma unroll
      for (int d = 0; d < 16; d++) dot += qxL[m * 17 + d] * kr[d];
      sL[m][p] = INV_SCALE * dot;
    }
  }
  __syncthreads();
  if (t < 64) {
    float mx = -3.4e38f;
    for (int p = 0; p < 256; p++) mx = fmaxf(mx, sL[t][p]);
    float sm = 0;
    for (int p = 0; p < 256; p++) sm += __expf(sL[t][p] - mx);
    rmaxL[t] = mx; rsinv[t] = 1.f / sm;
  }
  if (t < 256) {
    float mx = -3.4e38f;
    for (int m = 0; m < 64; m++) mx = fmaxf(mx, sL[m][t]);
    float sm = 0;
    for (int m = 0; m < 64; m++) sm += __expf(sL[m][t] - mx);
    cmaxL[t] = mx; csinv[t] = 1.f / sm;
  }
  __syncthreads();
  for (int idx = t; idx < 16384; idx += 512) {
    int m = idx >> 8, p = idx & 255;
    float x = sL[m][p];
    float val = __expf(x - rmaxL[m]) * rsinv[m] + __expf(x - cmaxL[p]) * csinv[p];
    out2[(size_t)bh * 16384 + idx] = val;
    sL[m][p] = val;
  }
  __syncthreads();
  if (t < 64) {
    float sm = 0;
    for (int p = 0; p < 256; p++) sm += sL[t][p];
    mrow[bh * 64 + t] = sm;
  }
}

// ---------------- mx1 = LN(mx + Lin(msgrow*vx rows)) ----------------
__global__ __launch_bounds__(128) void mx1_kernel(const float* __restrict__ mx, const float* __restrict__ mrow,
                                                  const float* __restrict__ vxl, const float* __restrict__ WT,
                                                  const float* __restrict__ bias, const float* __restrict__ g,
                                                  const float* __restrict__ bt, float* __restrict__ mx1) {
  int rg = blockIdx.x, t = threadIdx.x;
  int b = rg >> 6, rl = rg & 63, h = rl >> 3;
  __shared__ float nodeL[128];
  __shared__ float scr[2];
  int m = (rl & 7) * 8 + (t >> 4);
  float vxv = vxl[((size_t)(b * 64) + h * 8 + (m >> 3)) * 128 + (m & 7) * 16 + (t & 15)];
  nodeL[t] = mrow[(b * 8 + h) * 64 + m] * vxv;
  __syncthreads();
  float acc = bias[t];
#pragma unroll 8
  for (int i = 0; i < 128; i++) acc += nodeL[i] * WT[i * 128 + t];
  float val = mx[(size_t)rg * 128 + t] + acc;
  float v = waveSum(val);
  if ((t & 63) == 0) scr[t >> 6] = v;
  __syncthreads();
  float mean = (scr[0] + scr[1]) * (1.f / 128.f);
  __syncthreads();
  float dd = val - mean;
  v = waveSum(dd * dd);
  if ((t & 63) == 0) scr[t >> 6] = v;
  __syncthreads();
  float rstd = rsqrtf((scr[0] + scr[1]) * (1.f / 128.f) + 1e-5f);
  mx1[(size_t)rg * 128 + t] = dd * rstd * g[t] + bt[t];
}

// ---------------- K5 (fat-block MFMA, 32-row chunks, 4 blocks/CU): per (b,h,irow) ----------------
// 8 chunks of 32 pa vectors. LDS 38.7 KB -> 4 blocks/CU. Mapping: rloc in [0,32): n = rloc*8+q,
// colB = lr; e2[32][132] overlays kB exactly. Same total MFMA work as proven 64/128-row versions.
__global__ __launch_bounds__(512, 4) void k5_row(
    const float* __restrict__ prot_adj,
    const u16* __restrict__ msg_hi, const u16* __restrict__ msg_lo,
    const u16* __restrict__ wk_hi,   // fragment layout; lo at +16384
    const u16* __restrict__ wo_hi,   // fragment layout; lo at +16384
    const float* __restrict__ bk, const float* __restrict__ bo,
    const float* __restrict__ g1, const float* __restrict__ b1,
    const float* __restrict__ g4, const float* __restrict__ b4,
    float* __restrict__ rs128) {
  __shared__ __align__(16) unsigned char Lmem[38656];
  float (*paF)[132] = (float(*)[132])Lmem;                       // 32x132 f32 = 16896 B
  u16* kBh = (u16*)(Lmem + 16896);                               // 16x264 u16 = 8448 B
  u16* kBl = (u16*)(Lmem + 16896 + 8448);                        // 8448 B
  float (*e2)[132] = (float(*)[132])(Lmem + 16896);              // overlay on kB (16896 B)
  float* psum  = (float*)(Lmem + 33792);                         // 512 f
  float* meanL = (float*)(Lmem + 35840);                         // 32 f
  float* rstdL = (float*)(Lmem + 35968);                         // 32 f
  float* accL  = (float*)(Lmem + 36096);                         // 128 f
  float* scr2  = (float*)(Lmem + 36608);                         // 512 f (ends 38656)
  int t = threadIdx.x;
  int bid = (blockIdx.x & 7) * 256 + (blockIdx.x >> 3);
  int b = bid >> 8, h = (bid >> 5) & 7, irow_rel = bid & 31;
  int irow = h * 32 + irow_rel;
  int w = t >> 6, l = t & 63;
  const int lr = l & 15, lk = l >> 4;
  const int wr = w & 1, wq = w >> 1;       // row-half / q-quad for P3, P6
  const size_t mb = ((size_t)(b * 8 + h)) << 16;
  if (t < 128) accL[t] = 0.f;
  for (int chunk = 0; chunk < 8; chunk++) {
    __syncthreads();
    // P1: load 32 pa vectors (row irow, cols chunk*32 ..)
    {
      size_t pabase = (((size_t)(b * 256) + irow) * 256 + chunk * 32) * 128;
      const float4* src4 = (const float4*)(prot_adj + pabase);
      for (int idx = t; idx < 1024; idx += 512)
        *(float4*)&paF[idx >> 5][(idx & 31) * 4] = src4[idx];
    }
    __syncthreads();
    // P2: LN in place (paF is GEMM input AND residual base)
    ln32b_stats(paF, psum, meanL, rstdL, t);
    for (int idx = t; idx < 4096; idx += 512) {
      int r = idx >> 7, c = idx & 127;
      paF[r][c] = (paF[r][c] - meanL[r]) * rstdL[r] * g1[c] + b1[c];
    }
    __syncthreads();
    // P3: Lin_k [32 rows x 128 o]: wave w -> rows wr*16.., q = wq*2 + 0..1
    {
      f32x4 acc1[2];
#pragma unroll
      for (int qq = 0; qq < 2; qq++) acc1[qq] = (f32x4){0.f, 0.f, 0.f, 0.f};
#pragma unroll 1
      for (int kk = 0; kk < 4; kk++) {
        bf16x8 ah, al;
        split8(&paF[wr * 16 + lr][kk * 32 + lk * 8], ah, al);
#pragma unroll
        for (int qq = 0; qq < 2; qq++) {
          int q = wq * 2 + qq;
          bf16x8 bh = *(const bf16x8*)&wk_hi[q * 2048 + kk * 512 + l * 8];
          bf16x8 bl = *(const bf16x8*)&wk_hi[16384 + q * 2048 + kk * 512 + l * 8];
          acc1[qq] = MFMA(ah, bh, acc1[qq]);
          acc1[qq] = MFMA(al, bh, acc1[qq]);
          acc1[qq] = MFMA(ah, bl, acc1[qq]);
        }
      }
#pragma unroll
      for (int qq = 0; qq < 2; qq++) {
        int q = wq * 2 + qq;
        float bkv = bk[q * 16 + lr];
#pragma unroll
        for (int j = 0; j < 4; j++) {
          int rloc = wr * 16 + lk * 4 + j;
          int n = rloc * 8 + q;
          u16 hh, ll; split1(acc1[qq][j] + bkv, hh, ll);
          kBh[lr * 264 + n] = hh; kBl[lr * 264 + n] = ll;
        }
      }
    }
    __syncthreads();
    // P4: E-GEMM [256m x 16col] = msg[256x256] @ kB ; wave w -> m in [w*32, +32)
    f32x4 eacc[2];
#pragma unroll
    for (int mt = 0; mt < 2; mt++) eacc[mt] = (f32x4){0.f, 0.f, 0.f, 0.f};
#pragma unroll 1
    for (int kk = 0; kk < 8; kk++) {
      bf16x8 bhv = *(const bf16x8*)&kBh[lr * 264 + kk * 32 + lk * 8];
      bf16x8 blv = *(const bf16x8*)&kBl[lr * 264 + kk * 32 + lk * 8];
#pragma unroll
      for (int mt = 0; mt < 2; mt++) {
        size_t ro = mb + (size_t)((w * 2 + mt) * 4096 + kk * 512 + l * 8);
        bf16x8 ah = *(const bf16x8*)&msg_hi[ro];
        bf16x8 al = *(const bf16x8*)&msg_lo[ro];
        eacc[mt] = MFMA(ah, bhv, eacc[mt]);
        eacc[mt] = MFMA(al, bhv, eacc[mt]);
        eacc[mt] = MFMA(ah, blv, eacc[mt]);
      }
    }
    __syncthreads();  // all waves done reading kB before e2 overlay write
    // P5: scatter E -> e2[m>>3][(m&7)*16 + lr]
#pragma unroll
    for (int mt = 0; mt < 2; mt++)
#pragma unroll
      for (int j = 0; j < 4; j++) {
        int m = w * 32 + mt * 16 + lk * 4 + j;
        e2[m >> 3][(m & 7) * 16 + lr] = eacc[mt][j];
      }
    __syncthreads();
    // P6: Lin_out [32 rows x 128 o] + residual into paF
    {
      f32x4 oacc[2];
#pragma unroll
      for (int qq = 0; qq < 2; qq++) oacc[qq] = (f32x4){0.f, 0.f, 0.f, 0.f};
#pragma unroll 1
      for (int kk = 0; kk < 4; kk++) {
        bf16x8 ah, al;
        split8(&e2[wr * 16 + lr][kk * 32 + lk * 8], ah, al);
#pragma unroll
        for (int qq = 0; qq < 2; qq++) {
          int q = wq * 2 + qq;
          bf16x8 bh = *(const bf16x8*)&wo_hi[q * 2048 + kk * 512 + l * 8];
          bf16x8 bl = *(const bf16x8*)&wo_hi[16384 + q * 2048 + kk * 512 + l * 8];
          oacc[qq] = MFMA(ah, bh, oacc[qq]);
          oacc[qq] = MFMA(al, bh, oacc[qq]);
          oacc[qq] = MFMA(ah, bl, oacc[qq]);
        }
      }
      __syncthreads();
#pragma unroll
      for (int qq = 0; qq < 2; qq++) {
        int o = (wq * 2 + qq) * 16 + lr;
        float bv = bo[o];
#pragma unroll
        for (int j = 0; j < 4; j++) {
          int rloc = wr * 16 + lk * 4 + j;
          paF[rloc][o] = oacc[qq][j] + bv + paF[rloc][o];
        }
      }
    }
    __syncthreads();
    // P7: LN over 32 result rows, column partial reduce into accL
    ln32b_stats(paF, psum, meanL, rstdL, t);
    {
      int c = t & 127, rh = t >> 7;
      float part = 0;
#pragma unroll
      for (int rr = 0; rr < 8; rr++) {
        int r2 = rh * 8 + rr;
        part += (paF[r2][c] - meanL[r2]) * rstdL[r2];
      }
      scr2[rh * 128 + c] = part;
    }
    __syncthreads();
    if (t < 128) accL[t] += scr2[t] + scr2[128 + t] + scr2[256 + t] + scr2[384 + t];
  }
  __syncthreads();
  if (t < 128)
    atomicAdd(&rs128[(b * 8 + h) * 128 + t], g4[t] * accL[t] + 256.f * b4[t]);
}

// ---------------- ksum from rowsum128 ----------------
__global__ __launch_bounds__(128) void ksum_kernel(const float* __restrict__ rs128, const float* __restrict__ WT,
                                                   const float* __restrict__ bias, float* __restrict__ ks) {
  int bh = blockIdx.x, t = threadIdx.x;
  __shared__ float rsL[128];
  __shared__ float pcL[128];
  rsL[t] = rs128[bh * 128 + t];
  __syncthreads();
  float pc = 0;
#pragma unroll 8
  for (int i = 0; i < 128; i++) pc += rsL[i] * WT[i * 128 + t];
  pcL[t] = pc;
  __syncthreads();
  if (t < 16) {
    float kv = 0;
    for (int g8 = 0; g8 < 8; g8++) kv += pcL[g8 * 16 + t] + 8192.f * bias[g8 * 16 + t];
    ks[bh * 16 + t] = kv;
  }
}

// ---------------- se + vasum from ma rows ----------------
__global__ __launch_bounds__(256) void se_vasum(
    const float* __restrict__ ma, const float* __restrict__ WTqa, const float* __restrict__ bqa,
    const float* __restrict__ WTva, const float* __restrict__ bva,
    const float* __restrict__ ks, float* __restrict__ se, float* __restrict__ vas) {
  __shared__ __align__(16) float w[16384];
  __shared__ float rows[16 * 129];
  __shared__ float red[4096];
  int t = threadIdx.x, bid = blockIdx.x;
  int b = bid >> 8, iq = (bid >> 2) & 63, jb = bid & 3, j0 = jb * 16;
  int h = iq >> 3;
  float ksumv[16];
#pragma unroll
  for (int d = 0; d < 16; d++) ksumv[d] = ks[(b * 8 + h) * 16 + d];
  size_t rowbase = ((size_t)(b * 64 + iq) * 64 + j0) * 128;
  for (int idx = t; idx < 2048; idx += 256) rows[(idx >> 7) * 129 + (idx & 127)] = ma[rowbase + idx];
  for (int idx = t; idx < 16384; idx += 256) w[idx] = WTqa[idx];
  __syncthreads();
  int g8 = t >> 5, r = (t >> 1) & 15, iseg = t & 1;
  {
    float acc[16];
#pragma unroll
    for (int d = 0; d < 16; d++) acc[d] = 0.f;
    for (int ii = 0; ii < 64; ii++) {
      int i2 = iseg * 64 + ii;
      float pav = rows[r * 129 + i2];
      float wv[16];
      const float4* w4 = (const float4*)&w[i2 * 128 + g8 * 16];
      *(float4*)&wv[0] = w4[0]; *(float4*)&wv[4] = w4[1]; *(float4*)&wv[8] = w4[2]; *(float4*)&wv[12] = w4[3];
#pragma unroll
      for (int d = 0; d < 16; d++) acc[d] += pav * wv[d];
    }
    float sval = 0;
#pragma unroll
    for (int d = 0; d < 16; d++) sval += acc[d] * ksumv[d];
    red[(r * 8 + g8) * 2 + iseg] = sval;
    __syncthreads();
    if (t < 128) {
      int rr = t >> 3, gg = t & 7;
      float sv = red[(rr * 8 + gg) * 2] + red[(rr * 8 + gg) * 2 + 1];
      float bdot = 0;
#pragma unroll
      for (int d = 0; d < 16; d++) bdot += bqa[gg * 16 + d] * ksumv[d];
      sv += bdot;
      int jj = j0 + rr;
      int mm = (iq & 7) * 8 + (jj >> 3);
      int n2 = (jj & 7) * 8 + gg;
      se[((size_t)(b * 8 + h) * 64 + mm) * 64 + n2] = INV_SCALE * sv;
    }
    __syncthreads();
  }
  for (int idx = t; idx < 16384; idx += 256) w[idx] = WTva[idx];
  __syncthreads();
  {
    float acc[16];
#pragma unroll
    for (int d = 0; d < 16; d++) acc[d] = 0.f;
    for (int ii = 0; ii < 64; ii++) {
      int i2 = iseg * 64 + ii;
      float pav = rows[r * 129 + i2];
      float wv[16];
      const float4* w4 = (const float4*)&w[i2 * 128 + g8 * 16];
      *(float4*)&wv[0] = w4[0]; *(float4*)&wv[4] = w4[1]; *(float4*)&wv[8] = w4[2]; *(float4*)&wv[12] = w4[3];
#pragma unroll
      for (int d = 0; d < 16; d++) acc[d] += pav * wv[d];
    }
    if (iseg == 0) {
#pragma unroll
      for (int d = 0; d < 16; d++) acc[d] += bva[g8 * 16 + d];
    }
#pragma unroll
    for (int d = 0; d < 16; d++) red[t * 16 + d] = acc[d];
    __syncthreads();
    if (t < 32) {
      int mgrp = t >> 4, d = t & 15;
      float sm = 0;
      for (int gg = 0; gg < 8; gg++)
        for (int rr = mgrp * 8; rr < mgrp * 8 + 8; rr++) {
          sm += red[(gg * 32 + rr * 2) * 16 + d] + red[(gg * 32 + rr * 2 + 1) * 16 + d];
        }
      int mv = (iq & 7) * 8 + jb * 2 + mgrp;
      atomicAdd(&vas[((size_t)(b * 8 + h) * 64 + mv) * 16 + d], sm);
    }
  }
}

// ---------------- me2 from se ----------------
__global__ __launch_bounds__(256) void me2_kernel(const float* __restrict__ se, float* __restrict__ me2) {
  __shared__ float sL[64 * 65];
  __shared__ float rmaxL[64], rsinv[64], cmaxL[64], csinv[64];
  int bh = blockIdx.x, t = threadIdx.x;
  for (int idx = t; idx < 4096; idx += 256) sL[(idx >> 6) * 65 + (idx & 63)] = se[(size_t)bh * 4096 + idx];
  __syncthreads();
  if (t < 64) {
    float mx = -3.4e38f;
    for (int n = 0; n < 64; n++) mx = fmaxf(mx, sL[t * 65 + n]);
    float sm = 0;
    for (int n = 0; n < 64; n++) sm += __expf(sL[t * 65 + n] - mx);
    rmaxL[t] = mx; rsinv[t] = 1.f / sm;
  } else if (t < 128) {
    int n = t - 64;
    float mx = -3.4e38f;
    for (int m = 0; m < 64; m++) mx = fmaxf(mx, sL[m * 65 + n]);
    float sm = 0;
    for (int m = 0; m < 64; m++) sm += __expf(sL[m * 65 + n] - mx);
    cmaxL[n] = mx; csinv[n] = 1.f / sm;
  }
  __syncthreads();
  for (int idx = t; idx < 4096; idx += 256) {
    int m = idx >> 6, n = idx & 63;
    float x = sL[m * 65 + n];
    me2[(size_t)bh * 4096 + idx] = __expf(x - rmaxL[m]) * rsinv[m] + __expf(x - cmaxL[n]) * csinv[n];
  }
}

// ---------------- ma1 = LN(ma + Lin(me2*vasum rows)) ----------------
__global__ __launch_bounds__(256) void ma1_kernel(
    const float* __restrict__ ma, const float* __restrict__ me2, const float* __restrict__ vas,
    const float* __restrict__ WT, const float* __restrict__ bias,
    const float* __restrict__ g, const float* __restrict__ bt, float* __restrict__ ma1) {
  __shared__ __align__(16) float w[16384];
  __shared__ float rows[16 * 129];
  __shared__ float ored[4096];
  __shared__ float psum[256];
  __shared__ float meanL[16], rstdL[16];
  int t = threadIdx.x, bid = blockIdx.x;
  int b = bid >> 8, iq = (bid >> 2) & 63, jb = bid & 3, j0 = jb * 16;
  int h = iq >> 3;
  int bh64 = (b * 8 + h) * 64;
  size_t rowbase = ((size_t)(b * 64 + iq) * 64 + j0) * 128;
  for (int idx = t; idx < 2048; idx += 256) {
    int r = idx >> 7, c = idx & 127;
    int mm = (iq & 7) * 8 + jb * 2 + (r >> 3);
    int nn = (r & 7) * 8 + (c >> 4);
    rows[r * 129 + c] = me2[(size_t)(bh64 + mm) * 64 + nn] * vas[(size_t)(bh64 + mm) * 16 + (c & 15)];
  }
  for (int idx = t; idx < 16384; idx += 256) w[idx] = WT[idx];
  __syncthreads();
  int g8 = t >> 5, r = (t >> 1) & 15, iseg = t & 1;
  {
    float acc[16];
#pragma unroll
    for (int d = 0; d < 16; d++) acc[d] = 0.f;
    for (int ii = 0; ii < 64; ii++) {
      int i2 = iseg * 64 + ii;
      float pav = rows[r * 129 + i2];
      float wv[16];
      const float4* w4 = (const float4*)&w[i2 * 128 + g8 * 16];
      *(float4*)&wv[0] = w4[0]; *(float4*)&wv[4] = w4[1]; *(float4*)&wv[8] = w4[2]; *(float4*)&wv[12] = w4[3];
#pragma unroll
      for (int d = 0; d < 16; d++) acc[d] += pav * wv[d];
    }
    float* od = &ored[(iseg * 16 + r) * 128 + g8 * 16];
#pragma unroll
    for (int d = 0; d < 16; d++) od[d] = acc[d];
  }
  __syncthreads();
  for (int idx = t; idx < 2048; idx += 256) {
    int r2 = idx >> 7, c = idx & 127;
    rows[r2 * 129 + c] = ored[r2 * 128 + c] + ored[(16 + r2) * 128 + c] + bias[c] + ma[rowbase + idx];
  }
  __syncthreads();
  {
    int rr = t >> 4, seg = t & 15;
    float p = 0;
#pragma unroll
    for (int k = 0; k < 8; k++) p += rows[rr * 129 + seg * 8 + k];
    psum[rr * 16 + seg] = p;
    __syncthreads();
    if (t < 16) { float sm = 0; for (int k = 0; k < 16; k++) sm += psum[t * 16 + k]; meanL[t] = sm * (1.f / 128.f); }
    __syncthreads();
    float mu = meanL[rr];
    p = 0;
#pragma unroll
    for (int k = 0; k < 8; k++) { float d = rows[rr * 129 + seg * 8 + k] - mu; p += d * d; }
    psum[rr * 16 + seg] = p;
    __syncthreads();
    if (t < 16) { float sm = 0; for (int k = 0; k < 16; k++) sm += psum[t * 16 + k]; rstdL[t] = rsqrtf(sm * (1.f / 128.f) + 1e-5f); }
    __syncthreads();
  }
  for (int idx = t; idx < 2048; idx += 256) {
    int r2 = idx >> 7, c = idx & 127;
    ma1[rowbase + idx] = (rows[r2 * 129 + c] - meanL[r2]) * rstdL[r2] * g[c] + bt[c];
  }
}

// ---------------- MLP (pure-bf16 RNE MFMA, fragment weights) + residual + final LN ----------------
__global__ __launch_bounds__(256, 4) void mlp_mfma(
    const float* __restrict__ in,
    const u16* __restrict__ w1h,   // fragment [32q][4kk][64][8] RNE bf16
    const float* __restrict__ b1,
    const u16* __restrict__ w2h,   // fragment [8q][16kk][64][8] RNE bf16
    const float* __restrict__ b2,
    const float* __restrict__ g, const float* __restrict__ bt, float* __restrict__ out) {
  __shared__ __align__(16) float rowL[16][132];
  __shared__ __align__(16) u16 hh[16][520];
  __shared__ float psum[256];
  __shared__ float meanL[16], rstdL[16];
  int t = threadIdx.x, bid = blockIdx.x;
  int w = t >> 6, l = t & 63, lr = l & 15, lk = l >> 4;
  size_t base = (size_t)bid * 2048;
  {
    const float4* src4 = (const float4*)(in + base);
    for (int idx = t; idx < 512; idx += 256)
      *(float4*)&rowL[idx >> 5][(idx & 31) * 4] = src4[idx];
  }
  __syncthreads();
  {
    f32x4 acc1[8];
#pragma unroll
    for (int nt = 0; nt < 8; nt++) acc1[nt] = (f32x4){0.f, 0.f, 0.f, 0.f};
#pragma unroll 1
    for (int kk = 0; kk < 4; kk++) {
      bf16x8 ah = rne8(&rowL[lr][kk * 32 + lk * 8]);
#pragma unroll
      for (int nt = 0; nt < 8; nt++) {
        int q = w * 8 + nt;
        bf16x8 bh = *(const bf16x8*)&w1h[q * 2048 + kk * 512 + l * 8];
        acc1[nt] = MFMA(ah, bh, acc1[nt]);
      }
    }
#pragma unroll
    for (int nt = 0; nt < 8; nt++) {
      int o = w * 128 + nt * 16 + lr;
      float bb = b1[o];
#pragma unroll
      for (int j = 0; j < 4; j++) {
        int m = lk * 4 + j;
        float hv = 1.f / (1.f + __expf(-(acc1[nt][j] + bb)));
        hh[m][o] = rne1(hv);
      }
    }
  }
  __syncthreads();
  {
    f32x4 acc2[2];
#pragma unroll
    for (int nt = 0; nt < 2; nt++) acc2[nt] = (f32x4){0.f, 0.f, 0.f, 0.f};
#pragma unroll 1
    for (int kk = 0; kk < 16; kk++) {
      bf16x8 ah = *(const bf16x8*)&hh[lr][kk * 32 + lk * 8];
#pragma unroll
      for (int nt = 0; nt < 2; nt++) {
        int q = w * 2 + nt;
        bf16x8 bh = *(const bf16x8*)&w2h[q * 8192 + kk * 512 + l * 8];
        acc2[nt] = MFMA(ah, bh, acc2[nt]);
      }
    }
    __syncthreads();
#pragma unroll
    for (int nt = 0; nt < 2; nt++) {
      int c = w * 32 + nt * 16 + lr;
      float bb = b2[c];
#pragma unroll
      for (int j = 0; j < 4; j++) {
        int m = lk * 4 + j;
        rowL[m][c] = acc2[nt][j] + bb + rowL[m][c];
      }
    }
  }
  __syncthreads();
  {
    int rr = t >> 4, seg = t & 15;
    float p = 0;
#pragma unroll
    for (int k = 0; k < 8; k++) p += rowL[rr][seg * 8 + k];
    psum[rr * 16 + seg] = p;
    __syncthreads();
    if (t < 16) { float sm = 0; for (int k = 0; k < 16; k++) sm += psum[t * 16 + k]; meanL[t] = sm * (1.f / 128.f); }
    __syncthreads();
    float mu = meanL[rr];
    p = 0;
#pragma unroll
    for (int k = 0; k < 8; k++) { float d = rowL[rr][seg * 8 + k] - mu; p += d * d; }
    psum[rr * 16 + seg] = p;
    __syncthreads();
    if (t < 16) { float sm = 0; for (int k = 0; k < 16; k++) sm += psum[t * 16 + k]; rstdL[t] = rsqrtf(sm * (1.f / 128.f) + 1e-5f); }
    __syncthreads();
  }
  for (int idx = t; idx < 2048; idx += 256) {
    int r2 = idx >> 7, cc = idx & 127;
    out[base + idx] = (rowL[r2][cc] - meanL[r2]) * rstdL[r2] * g[cc] + bt[cc];
  }
}

extern "C" void kernel_launch(void* const* d_in, const int* in_sizes, int n_in,
                              void* d_out, int out_size, void* d_ws, size_t ws_size,
                              hipStream_t stream) {
  (void)in_sizes; (void)n_in; (void)out_size; (void)ws_size;
  const float* mol_annot  = (const float*)d_in[0];
  const float* prot_annot = (const float*)d_in[1];
  const float* mol_adj    = (const float*)d_in[2];
  const float* prot_adj   = (const float*)d_in[3];
  const float* att_w = (const float*)d_in[4];
  const float* att_b = (const float*)d_in[5];
  const float* dec_w = (const float*)d_in[6];
  const float* dec_b = (const float*)d_in[7];
  const float* mlp_w1 = (const float*)d_in[8];
  const float* mlp_b1 = (const float*)d_in[9];
  const float* mlp_w2 = (const float*)d_in[10];
  const float* mlp_b2 = (const float*)d_in[11];
  const float* ln_g = (const float*)d_in[12];
  const float* ln_b = (const float*)d_in[13];
  float* out = (float*)d_out;
  float* ws = (float*)d_ws;

  const u16* wk_hi = (const u16*)(ws + WT_ATT + 16384);
  const u16* wo_hi = (const u16*)(ws + WT_ATT + 3 * 16384);
  u16* msg_hi = (u16*)(ws + O_MA1);          // O_MA1 region free until ma1_kernel
  u16* msg_lo = msg_hi + 4194304;
  float* pmaxp = ws + O_MSG;                 // O_MSG region free (msg f32 eliminated)
  float* psump = ws + O_MSG + 131072;

  hipMemsetAsync(ws + O_RS, 0, 8192 * sizeof(float), stream);
  hipMemsetAsync(ws + O_VAS, 0, 65536 * sizeof(float), stream);
  prep_wt<<<17, 256, 0, stream>>>(att_w, dec_w, mlp_w1, mlp_w2, ws);
  ln_rows4<<<512, 128, 0, stream>>>(prot_annot, ws + O_PX, ln_g + 384, ln_b + 384);
  ln_rows4<<<128, 128, 0, stream>>>(mol_annot, ws + O_MX, ln_g + 256, ln_b + 256);
  ln_rows4<<<8192, 128, 0, stream>>>(mol_adj, ws + O_MA, ln_g, ln_b);
  lin_rows2<<<2048, 128, 0, stream>>>(ws + O_PX, ws + O_QL, ws + WT_ATT, att_b,
                                      ws + O_VL, ws + WT_ATT + 2 * 16384, att_b + 256);
  lin_rows2<<<512, 128, 0, stream>>>(ws + O_MX, ws + O_QXL, ws + WT_DEC, dec_b,
                                     ws + O_VXL, ws + WT_DEC + 2 * 16384, dec_b + 256);
  k1_fold<<<16384, 256, 0, stream>>>(prot_adj, ws + O_QL, att_w + 16384, att_b + 128,
                                     ln_g + 128, ln_b + 128, ws + O_S);
  col_part<<<512, 256, 0, stream>>>(ws + O_S, pmaxp, psump);
  msg_tiles<<<512, 256, 0, stream>>>(ws + O_S, pmaxp, psump, ws + O_VL, msg_hi, msg_lo, ws + O_NH);
  // fused px1 + kx linear (px1 never materialized)
  px1k_kernel<<<2048, 128, 0, stream>>>(ws + O_PX, ws + O_NH, ws + WT_ATT + 4 * 16384, att_b + 512,
                                        ln_g + 640, ln_b + 640, ws + WT_DEC + 16384, dec_b + 128,
                                        ws + O_KXL);
  s2_fused<<<64, 512, 0, stream>>>(ws + O_QXL, ws + O_KXL, out + OUT2_OFF, ws + O_MROW);
  mx1_kernel<<<512, 128, 0, stream>>>(ws + O_MX, ws + O_MROW, ws + O_VXL, ws + WT_DEC + 6 * 16384,
                                      dec_b + 768, ln_g + 896, ln_b + 896, ws + O_MX1);
  k5_row<<<2048, 512, 0, stream>>>(prot_adj, msg_hi, msg_lo, wk_hi, wo_hi,
                                   att_b + 128, att_b + 384,
                                   ln_g + 128, ln_b + 128, ln_g + 512, ln_b + 512, ws + O_RS);
  ksum_kernel<<<64, 128, 0, stream>>>(ws + O_RS, ws + WT_DEC + 4 * 16384, dec_b + 512, ws + O_KS);
  se_vasum<<<2048, 256, 0, stream>>>(ws + O_MA, ws + WT_DEC + 3 * 16384, dec_b + 384,
                                     ws + WT_DEC + 5 * 16384, dec_b + 640, ws + O_KS, ws + O_SE, ws + O_VAS);
  me2_kernel<<<64, 256, 0, stream>>>(ws + O_SE, ws + O_ME2);
  ma1_kernel<<<2048, 256, 0, stream>>>(ws + O_MA, ws + O_ME2, ws + O_VAS, ws + WT_DEC + 7 * 16384,
                                       dec_b + 896, ln_g + 768, ln_b + 768, ws + O_MA1);
  mlp_mfma<<<2048, 256, 0, stream>>>(ws + O_MA1, (const u16*)(ws + WT_M1), mlp_b1,
                                     (const u16*)(ws + WT_M2), mlp_b2,
                                     ln_g + 1024, ln_b + 1024, out);
  mlp_mfma<<<32, 256, 0, stream>>>(ws + O_MX1, (const u16*)(ws + WT_M1 + 65536), mlp_b1 + 512,
                                   (const u16*)(ws + WT_M2 + 65536), mlp_b2 + 128,
                                   ln_g + 1152, ln_b + 1152, out + OUT1_OFF);
}

// Round 15
// 839.611 us; speedup vs baseline: 1.0845x; 1.0845x over previous
//
#include <hip/hip_runtime.h>
#include <hip/hip_bf16.h>
#include <math.h>

// Shapes: B=8, N=64, P=256, DIM=128, HEADS=8, DK=16, HID=512
#define INV_SCALE 3.3635856610148585f  // 128**0.25

typedef float f32x4 __attribute__((ext_vector_type(4)));
typedef short bf16x8 __attribute__((ext_vector_type(8)));
typedef unsigned short u16;
#define MFMA(a_, b_, c_) __builtin_amdgcn_mfma_f32_16x16x32_bf16(a_, b_, c_, 0, 0, 0)

// ---------------- ws layout (float offsets) ----------------
constexpr int WT_ATT = 0;                 // 5 * 16384 (slots 1,3 = bf16 hi/lo FRAGMENT layout)
constexpr int WT_DEC = 81920;             // 8 * 16384
constexpr int WT_M1  = 212992;            // 2 * 65536 (bf16 RNE fragment [32q][4kk], lo slot unused)
constexpr int WT_M2  = 344064;            // 2 * 65536 (bf16 RNE fragment [8q][16kk], lo slot unused)
constexpr int O_PX   = 475136;            // 8*256*128
constexpr int O_MX   = 737280;            // 8*64*128
constexpr int O_MA   = 802816;            // 8*64*64*128
constexpr int O_QL   = 4997120;           // 8*256*128
constexpr int O_VL   = 5259264;
constexpr int O_QXL  = 5521408;
constexpr int O_VXL  = 5586944;
constexpr int O_KXL  = 5652480;
constexpr int O_PX1  = 5914624;
constexpr int O_MX1  = 6176768;
constexpr int O_S    = 6242304;           // 8*8*256*256
constexpr int O_MSG  = 10469376;          // free region: col partial max/sum live here
constexpr int O_NH   = 14663680;          // 8*8*256*16
constexpr int O_RS   = 14925824;          // 8*8*128
constexpr int O_KS   = 14934016;          // 8*8*16
constexpr int O_SE   = 14935040;          // 8*8*64*64
constexpr int O_ME2  = 15197184;
constexpr int O_VAS  = 15459328;          // 8*8*64*16
constexpr int O_MROW = 15524864;          // 8*8*64
constexpr int O_MA1  = 16577536;          // 8*64*64*128 ; BEFORE ma1: msg bf16 hi/lo FRAGMENT layout
// total = 20771840 floats (~79 MB, proven)

constexpr int OUT1_OFF = 4194304;         // node_hidden
constexpr int OUT2_OFF = 4259840;         // attn_dec

__device__ __forceinline__ float waveSum(float v) {
#pragma unroll
  for (int o = 32; o > 0; o >>= 1) v += __shfl_down(v, o, 64);
  return v;
}

__device__ __forceinline__ void split1(float a, u16& h, u16& l) {
  unsigned ua = __float_as_uint(a) & 0xffff0000u;
  h = (u16)(ua >> 16);
  float al = a - __uint_as_float(ua);
  l = (u16)(__float_as_uint(al) >> 16);
}
__device__ __forceinline__ void split8(const float* p, bf16x8& hi, bf16x8& lo) {
#pragma unroll
  for (int i = 0; i < 8; i++) {
    float a = p[i];
    unsigned ua = __float_as_uint(a) & 0xffff0000u;
    float al = a - __uint_as_float(ua);
    hi[i] = (short)(u16)(ua >> 16);
    lo[i] = (short)(u16)(__float_as_uint(al) >> 16);
  }
}
__device__ __forceinline__ u16 rne1(float a) {
  unsigned u = __float_as_uint(a);
  u += 0x7fffu + ((u >> 16) & 1u);
  return (u16)(u >> 16);
}
__device__ __forceinline__ bf16x8 rne8(const float* p) {
  bf16x8 h;
#pragma unroll
  for (int i = 0; i < 8; i++) h[i] = (short)rne1(p[i]);
  return h;
}

// ---------------- weight prep (fragment layouts for MFMA-consumed weights) ----------------
__global__ __launch_bounds__(256) void prep_wt(
    const float* __restrict__ att_w, const float* __restrict__ dec_w,
    const float* __restrict__ mlp_w1, const float* __restrict__ mlp_w2,
    float* __restrict__ ws) {
  int seg = blockIdx.x, t = threadIdx.x;
  if (seg < 5) {
    const float* w = att_w + seg * 16384;
    if (seg == 1 || seg == 3) {   // fragment layout [8q][4kk][64lane][8e], hi; lo at +16384 (3-term split)
      u16* oh = (u16*)(ws + WT_ATT + seg * 16384);
      for (int idx = t; idx < 16384; idx += 256) {
        int e = idx & 7, lane = (idx >> 3) & 63, kk = (idx >> 9) & 3, q = idx >> 11;
        int o = q * 16 + (lane & 15), i = kk * 32 + (lane >> 4) * 8 + e;
        u16 hh, ll; split1(w[o * 128 + i], hh, ll);
        oh[idx] = hh; oh[16384 + idx] = ll;
      }
    } else {
      float* o = ws + WT_ATT + seg * 16384;
      for (int idx = t; idx < 16384; idx += 256) o[idx] = w[(idx & 127) * 128 + (idx >> 7)];
    }
  } else if (seg < 13) {
    int k = seg - 5;
    const float* w = dec_w + k * 16384;
    float* o = ws + WT_DEC + k * 16384;
    for (int idx = t; idx < 16384; idx += 256) o[idx] = w[(idx & 127) * 128 + (idx >> 7)];
  } else if (seg < 15) {
    int k = seg - 13;
    const float* w = mlp_w1 + k * 65536;   // [512][128] -> fragment [32q][4kk][64][8], RNE bf16
    u16* oh = (u16*)(ws + WT_M1 + k * 65536);
    for (int idx = t; idx < 65536; idx += 256) {
      int e = idx & 7, lane = (idx >> 3) & 63, kk = (idx >> 9) & 3, q = idx >> 11;
      int o = q * 16 + (lane & 15), i = kk * 32 + (lane >> 4) * 8 + e;
      oh[idx] = rne1(w[o * 128 + i]); oh[65536 + idx] = 0;
    }
  } else {
    int k = seg - 15;
    const float* w = mlp_w2 + k * 65536;   // [128][512] -> fragment [8q][16kk][64][8], RNE bf16
    u16* oh = (u16*)(ws + WT_M2 + k * 65536);
    for (int idx = t; idx < 65536; idx += 256) {
      int e = idx & 7, lane = (idx >> 3) & 63, kk = (idx >> 9) & 15, q = idx >> 13;
      int o = q * 16 + (lane & 15), i = kk * 32 + (lane >> 4) * 8 + e;
      oh[idx] = rne1(w[o * 512 + i]); oh[65536 + idx] = 0;
    }
  }
}

// ---------------- vectorized LayerNorm: 4 rows per 128-thread block, float4 lanes ----------------
__global__ __launch_bounds__(128) void ln_rows4(const float* __restrict__ in, float* __restrict__ out,
                                                const float* __restrict__ g, const float* __restrict__ b) {
  int t = threadIdx.x;
  size_t row = (size_t)blockIdx.x * 4 + (t >> 5);
  int c4 = (t & 31) * 4;
  float4 x = *(const float4*)&in[row * 128 + c4];
  float s = x.x + x.y + x.z + x.w;
#pragma unroll
  for (int o = 16; o > 0; o >>= 1) s += __shfl_xor(s, o, 64);
  float mean = s * (1.f / 128.f);
  float dx = x.x - mean, dy = x.y - mean, dz = x.z - mean, dw = x.w - mean;
  float v = dx * dx + dy * dy + dz * dz + dw * dw;
#pragma unroll
  for (int o = 16; o > 0; o >>= 1) v += __shfl_xor(v, o, 64);
  float rstd = rsqrtf(v * (1.f / 128.f) + 1e-5f);
  float4 gv = *(const float4*)&g[c4];
  float4 bv = *(const float4*)&b[c4];
  float4 o4;
  o4.x = dx * rstd * gv.x + bv.x;
  o4.y = dy * rstd * gv.y + bv.y;
  o4.z = dz * rstd * gv.z + bv.z;
  o4.w = dw * rstd * gv.w + bv.w;
  *(float4*)&out[row * 128 + c4] = o4;
}

// ---------------- dual small linear ----------------
__global__ __launch_bounds__(128) void lin_rows2(const float* __restrict__ in,
                                                 float* __restrict__ out1, const float* __restrict__ WT1,
                                                 const float* __restrict__ b1v,
                                                 float* __restrict__ out2, const float* __restrict__ WT2,
                                                 const float* __restrict__ b2v) {
  int row = blockIdx.x, t = threadIdx.x;
  __shared__ float rl[128];
  rl[t] = in[(size_t)row * 128 + t];
  __syncthreads();
  float a1 = b1v[t], a2 = b2v[t];
#pragma unroll 8
  for (int i = 0; i < 128; i++) {
    float rv = rl[i];
    a1 += rv * WT1[i * 128 + t];
    a2 += rv * WT2[i * 128 + t];
  }
  out1[(size_t)row * 128 + t] = a1;
  out2[(size_t)row * 128 + t] = a2;
}

// ---------------- shared LN-over-32-rows helper (256 threads) ----------------
__device__ __forceinline__ void ln32_stats(float (*tile)[132], float* psum, float* meanL, float* rstdL,
                                           int t) {
  int r = t >> 3, seg = t & 7;
  float p = 0;
#pragma unroll
  for (int k = 0; k < 16; k++) p += tile[r][seg * 16 + k];
  psum[r * 8 + seg] = p;
  __syncthreads();
  if (t < 32) { float sm = 0; for (int k = 0; k < 8; k++) sm += psum[t * 8 + k]; meanL[t] = sm * (1.f / 128.f); }
  __syncthreads();
  float mu = meanL[r];
  p = 0;
#pragma unroll
  for (int k = 0; k < 16; k++) { float d = tile[r][seg * 16 + k] - mu; p += d * d; }
  psum[r * 8 + seg] = p;
  __syncthreads();
  if (t < 32) { float sm = 0; for (int k = 0; k < 8; k++) sm += psum[t * 8 + k]; rstdL[t] = rsqrtf(sm * (1.f / 128.f) + 1e-5f); }
  __syncthreads();
}

// ---------------- LN-over-64-rows helper (512 threads, 8 thr/row x 16 elems) ----------------
__device__ __forceinline__ void ln64_stats(float (*tile)[132], float* psum, float* meanL, float* rstdL,
                                           int t) {
  int r = t >> 3, seg = t & 7;
  float p = 0;
#pragma unroll
  for (int k = 0; k < 16; k++) p += tile[r][seg * 16 + k];
  psum[r * 8 + seg] = p;
  __syncthreads();
  if (t < 64) { float sm = 0; for (int k = 0; k < 8; k++) sm += psum[t * 8 + k]; meanL[t] = sm * (1.f / 128.f); }
  __syncthreads();
  float mu = meanL[r];
  p = 0;
#pragma unroll
  for (int k = 0; k < 16; k++) { float d = tile[r][seg * 16 + k] - mu; p += d * d; }
  psum[r * 8 + seg] = p;
  __syncthreads();
  if (t < 64) { float sm = 0; for (int k = 0; k < 8; k++) sm += psum[t * 8 + k]; rstdL[t] = rsqrtf(sm * (1.f / 128.f) + 1e-5f); }
  __syncthreads();
}

// ---------------- K1 (q-folded VALU): s[b,h,m,n] = INV * (paLN @ Wq'^T + bq') ----------------
__global__ __launch_bounds__(256, 8) void k1_fold(
    const float* __restrict__ prot_adj, const float* __restrict__ q_lin,
    const float* __restrict__ wk_orig,  // att_w slot 1, [o=128][i=128] f32
    const float* __restrict__ bk,
    const float* __restrict__ g1, const float* __restrict__ b1,
    float* __restrict__ sdst) {
  __shared__ __align__(16) float paF[32][132];
  __shared__ float wq[8][132];
  __shared__ float qL[16];
  __shared__ float psum[256];
  __shared__ float meanL[32], rstdL[32];
  int t = threadIdx.x, bid = blockIdx.x;
  int b = bid >> 11, h = (bid >> 8) & 7, ai = bid & 255;
  int irow = h * 32 + (ai >> 3), j0 = (ai & 7) * 32;
  int mq = (ai >> 3) * 8 + (ai & 7);
  size_t pabase = (((size_t)(b * 256) + irow) * 256 + j0) * 128;
  {
    const float4* src4 = (const float4*)(prot_adj + pabase);
    for (int idx = t; idx < 1024; idx += 256)
      *(float4*)&paF[idx >> 5][(idx & 31) * 4] = src4[idx];
  }
  if (t < 16) qL[t] = q_lin[((size_t)(b * 256) + h * 32 + (mq >> 3)) * 128 + (mq & 7) * 16 + t];
  __syncthreads();
#pragma unroll
  for (int k = 0; k < 4; k++) {
    int o = t + k * 256;
    int g8 = o >> 7, c = o & 127;
    float s = 0;
#pragma unroll
    for (int d = 0; d < 16; d++) s += qL[d] * wk_orig[(g8 * 16 + d) * 128 + c];
    wq[g8][c] = s;
  }
  ln32_stats(paF, psum, meanL, rstdL, t);
  for (int idx = t; idx < 4096; idx += 256) {
    int r = idx >> 7, c = idx & 127;
    paF[r][c] = (paF[r][c] - meanL[r]) * rstdL[r] * g1[c] + b1[c];
  }
  __syncthreads();
  int r = t >> 3, g8 = t & 7;
  float acc = 0;
#pragma unroll
  for (int d = 0; d < 16; d++) acc += qL[d] * bk[g8 * 16 + d];
#pragma unroll 8
  for (int c = 0; c < 128; c++) acc += paF[r][c] * wq[g8][c];
  size_t sb = ((size_t)((b * 8 + h) * 256 + mq)) * 256;
  sdst[sb + t] = INV_SCALE * acc;
}

// ---------------- column partial stats of s ----------------
__global__ __launch_bounds__(256) void col_part(const float* __restrict__ s, float* __restrict__ pmax,
                                                float* __restrict__ psumv) {
  int bid = blockIdx.x, t = threadIdx.x;
  int bh = bid >> 3, ch = bid & 7;
  const float* sp = s + ((size_t)(bh * 256) + ch * 32) * 256 + t;
  float rm = -3.4e38f, rs = 0.f;
  for (int r = 0; r < 32; r++) {
    float x = sp[(size_t)r * 256];
    float nm = fmaxf(rm, x);
    rs = rs * __expf(rm - nm) + __expf(x - nm);
    rm = nm;
  }
  pmax[(bh * 8 + ch) * 256 + t] = rm;
  psumv[(bh * 8 + ch) * 256 + t] = rs;
}

// ---------------- message tiles: softmaxes + diag; write bf16 hi/lo FRAGMENTS; fused nh MFMA ----------------
__global__ __launch_bounds__(256, 1) void msg_tiles(const float* __restrict__ s,
                                                    const float* __restrict__ pmax, const float* __restrict__ psumv,
                                                    const float* __restrict__ v_lin,
                                                    u16* __restrict__ mhi, u16* __restrict__ mlo,
                                                    float* __restrict__ nh) {
  __shared__ __align__(16) float rowT[32][260];
  __shared__ float sT[256][33];
  __shared__ __align__(16) u16 vTh[16][264];
  __shared__ __align__(16) u16 vTl[16][264];
  __shared__ float red[256];
  __shared__ float rmax[32], rsinv[32], cmaxL[32], csinvL[32];
  int bid = blockIdx.x, t = threadIdx.x;
  int bh = bid >> 3, m0 = (bid & 7) * 32;
  int b = bh >> 3, h = bh & 7;
  size_t sbase = (size_t)(bh * 256) * 256;
  for (int idx = t; idx < 2048; idx += 256) {
    int r = idx >> 6, c4 = (idx & 63) * 4;
    *(float4*)&rowT[r][c4] = *(const float4*)&s[sbase + (size_t)(m0 + r) * 256 + c4];
  }
  for (int idx = t; idx < 2048; idx += 256) {
    int n = idx >> 3, mc4 = (idx & 7) * 4;
    float4 v4 = *(const float4*)&s[sbase + (size_t)n * 256 + m0 + mc4];
    sT[n][mc4] = v4.x; sT[n][mc4 + 1] = v4.y; sT[n][mc4 + 2] = v4.z; sT[n][mc4 + 3] = v4.w;
  }
  {
    const float4* vb4 = (const float4*)(v_lin + ((size_t)(b * 256) + h * 32) * 128);
    for (int idx = t; idx < 1024; idx += 256) {
      float4 v4 = vb4[idx];
#pragma unroll
      for (int i = 0; i < 4; i++) {
        int flat = idx * 4 + i;
        int d = flat & 15, n = flat >> 4;
        u16 hh2, ll2; split1(((const float*)&v4)[i], hh2, ll2);
        vTh[d][n] = hh2; vTl[d][n] = ll2;
      }
    }
  }
  __syncthreads();
  {
    int r = t >> 3, sg = t & 7;
    float pm = -3.4e38f;
    for (int k = 0; k < 32; k++) pm = fmaxf(pm, rowT[r][sg * 32 + k]);
    red[t] = pm;
    __syncthreads();
    if (t < 32) { float mm = red[t * 8]; for (int k = 1; k < 8; k++) mm = fmaxf(mm, red[t * 8 + k]); rmax[t] = mm; }
    __syncthreads();
    float mm = rmax[r], ps = 0;
    for (int k = 0; k < 32; k++) ps += __expf(rowT[r][sg * 32 + k] - mm);
    red[t] = ps;
    __syncthreads();
    if (t < 32) { float sm = 0; for (int k = 0; k < 8; k++) sm += red[t * 8 + k]; rsinv[t] = 1.f / sm; }
    if (t >= 64 && t < 96) {
      int mc = t - 64, col = m0 + mc;
      float cm = -3.4e38f;
      for (int c2 = 0; c2 < 8; c2++) cm = fmaxf(cm, pmax[(bh * 8 + c2) * 256 + col]);
      float cs = 0;
      for (int c2 = 0; c2 < 8; c2++) cs += psumv[(bh * 8 + c2) * 256 + col] * __expf(pmax[(bh * 8 + c2) * 256 + col] - cm);
      cmaxL[mc] = cm; csinvL[mc] = 1.f / cs;
    }
    __syncthreads();
  }
  for (int idx = t; idx < 8192; idx += 256) {
    int r = idx >> 8, n = idx & 255;
    float x = rowT[r][n];
    float outv = __expf(x - rmax[r]) * rsinv[r];
    float inval = __expf(sT[n][r] - cmaxL[r]) * csinvL[r];
    rowT[r][n] = (n == m0 + r) ? inval : (outv + inval);
  }
  __syncthreads();
  // fragment store: frag (bh, mtile, kk, lane) ; lane = lk*16+lr holds msg[mtile*16+lr][kk*32+lk*8+e]
  for (int fi = t; fi < 1024; fi += 256) {
    int r = fi >> 5, fc = fi & 31;
    int m = m0 + r;
    int lane = (fc & 3) * 16 + (m & 15);
    size_t base = (size_t)bh * 65536 + (size_t)(m >> 4) * 4096 + (size_t)(fc >> 2) * 512 + lane * 8;
    bf16x8 h8, l8;
    split8(&rowT[r][fc * 8], h8, l8);
    *(bf16x8*)&mhi[base] = h8;
    *(bf16x8*)&mlo[base] = l8;
  }
  // fused nh = msg_tile @ v : [32m x 16d x 256n], waves 0-1 (reads rowT only)
  int w = t >> 6, l = t & 63, lr = l & 15, lk = l >> 4;
  if (w < 2) {
    f32x4 acc = (f32x4){0.f, 0.f, 0.f, 0.f};
#pragma unroll
    for (int kk = 0; kk < 8; kk++) {
      bf16x8 ah, al;
      split8(&rowT[w * 16 + lr][kk * 32 + lk * 8], ah, al);
      bf16x8 bhv = *(const bf16x8*)&vTh[lr][kk * 32 + lk * 8];
      bf16x8 blv = *(const bf16x8*)&vTl[lr][kk * 32 + lk * 8];
      acc = MFMA(ah, bhv, acc);
      acc = MFMA(al, bhv, acc);
      acc = MFMA(ah, blv, acc);
    }
#pragma unroll
    for (int j = 0; j < 4; j++)
      nh[((size_t)(bh * 256) + m0 + w * 16 + lk * 4 + j) * 16 + lr] = acc[j];
  }
}

// ---------------- fused px1 = LN(px + Lin(nh)) -> kxl = Lin(px1)  (px1 never materialized) ----------------
__global__ __launch_bounds__(128) void px1k_kernel(const float* __restrict__ px, const float* __restrict__ nh,
                                                   const float* __restrict__ WTo, const float* __restrict__ bo,
                                                   const float* __restrict__ g, const float* __restrict__ bt,
                                                   const float* __restrict__ WTk, const float* __restrict__ bkx,
                                                   float* __restrict__ kxl) {
  int p = blockIdx.x, t = threadIdx.x;
  int b = p >> 8, pl = p & 255, h = pl >> 5;
  __shared__ float nodeL[128];
  __shared__ float px1L[128];
  __shared__ float scr[2];
  nodeL[t] = nh[((size_t)(b * 8 + h) * 256 + ((pl & 31) * 8 + (t >> 4))) * 16 + (t & 15)];
  __syncthreads();
  float acc = bo[t];
#pragma unroll 8
  for (int i = 0; i < 128; i++) acc += nodeL[i] * WTo[i * 128 + t];
  float val = px[(size_t)p * 128 + t] + acc;
  float v = waveSum(val);
  if ((t & 63) == 0) scr[t >> 6] = v;
  __syncthreads();
  float mean = (scr[0] + scr[1]) * (1.f / 128.f);
  __syncthreads();
  float dd = val - mean;
  v = waveSum(dd * dd);
  if ((t & 63) == 0) scr[t >> 6] = v;
  __syncthreads();
  float rstd = rsqrtf((scr[0] + scr[1]) * (1.f / 128.f) + 1e-5f);
  px1L[t] = dd * rstd * g[t] + bt[t];
  __syncthreads();
  float a2 = bkx[t];
#pragma unroll 8
  for (int i = 0; i < 128; i++) a2 += px1L[i] * WTk[i * 128 + t];
  kxl[(size_t)p * 128 + t] = a2;
}

// ---------------- fused s2 + message2 + msgrow (512 threads) ----------------
__global__ __launch_bounds__(512, 1) void s2_fused(const float* __restrict__ qxl, const float* __restrict__ kxl,
                                                   float* __restrict__ out2, float* __restrict__ mrow) {
  __shared__ float kxL[256 * 17];
  __shared__ float qxL[64 * 17];
  __shared__ float sL[64][257];
  __shared__ float rmaxL[64], rsinv[64];
  __shared__ float cmaxL[256], csinv[256];
  int bh = blockIdx.x, t = threadIdx.x;
  int b = bh >> 3, h = bh & 7;
  for (int idx = t; idx < 4096; idx += 512) {
    int pl = idx >> 7, cc = idx & 127;
    kxL[(pl * 8 + (cc >> 4)) * 17 + (cc & 15)] = kxl[((size_t)(b * 256) + h * 32 + pl) * 128 + cc];
  }
  for (int idx = t; idx < 1024; idx += 512) {
    int rl = idx >> 7, cc = idx & 127;
    qxL[(rl * 8 + (cc >> 4)) * 17 + (cc & 15)] = qxl[((size_t)(b * 64) + h * 8 + rl) * 128 + cc];
  }
  __syncthreads();
  {
    int p = t & 255, mh = t >> 8;   // 2 threads per column, 32 rows each
    float kr[16];
#pragma unroll
    for (int d = 0; d < 16; d++) kr[d] = kxL[p * 17 + d];
    for (int m = mh * 32; m < mh * 32 + 32; m++) {
      float dot = 0;
#pragma unroll
      for (int d = 0; d < 16; d++) dot += qxL[m * 17 + d] * kr[d];
      sL[m][p] = INV_SCALE * dot;
    }
  }
  __syncthreads();
  if (t < 64) {
    float mx = -3.4e38f;
    for (int p = 0; p < 256; p++) mx = fmaxf(mx, sL[t][p]);
    float sm = 0;
    for (int p = 0; p < 256; p++) sm += __expf(sL[t][p] - mx);
    rmaxL[t] = mx; rsinv[t] = 1.f / sm;
  }
  if (t < 256) {
    float mx = -3.4e38f;
    for (int m = 0; m < 64; m++) mx = fmaxf(mx, sL[m][t]);
    float sm = 0;
    for (int m = 0; m < 64; m++) sm += __expf(sL[m][t] - mx);
    cmaxL[t] = mx; csinv[t] = 1.f / sm;
  }
  __syncthreads();
  for (int idx = t; idx < 16384; idx += 512) {
    int m = idx >> 8, p = idx & 255;
    float x = sL[m][p];
    float val = __expf(x - rmaxL[m]) * rsinv[m] + __expf(x - cmaxL[p]) * csinv[p];
    out2[(size_t)bh * 16384 + idx] = val;
    sL[m][p] = val;
  }
  __syncthreads();
  if (t < 64) {
    float sm = 0;
    for (int p = 0; p < 256; p++) sm += sL[t][p];
    mrow[bh * 64 + t] = sm;
  }
}

// ---------------- mx1 = LN(mx + Lin(msgrow*vx rows)) ----------------
__global__ __launch_bounds__(128) void mx1_kernel(const float* __restrict__ mx, const float* __restrict__ mrow,
                                                  const float* __restrict__ vxl, const float* __restrict__ WT,
                                                  const float* __restrict__ bias, const float* __restrict__ g,
                                                  const float* __restrict__ bt, float* __restrict__ mx1) {
  int rg = blockIdx.x, t = threadIdx.x;
  int b = rg >> 6, rl = rg & 63, h = rl >> 3;
  __shared__ float nodeL[128];
  __shared__ float scr[2];
  int m = (rl & 7) * 8 + (t >> 4);
  float vxv = vxl[((size_t)(b * 64) + h * 8 + (m >> 3)) * 128 + (m & 7) * 16 + (t & 15)];
  nodeL[t] = mrow[(b * 8 + h) * 64 + m] * vxv;
  __syncthreads();
  float acc = bias[t];
#pragma unroll 8
  for (int i = 0; i < 128; i++) acc += nodeL[i] * WT[i * 128 + t];
  float val = mx[(size_t)rg * 128 + t] + acc;
  float v = waveSum(val);
  if ((t & 63) == 0) scr[t >> 6] = v;
  __syncthreads();
  float mean = (scr[0] + scr[1]) * (1.f / 128.f);
  __syncthreads();
  float dd = val - mean;
  v = waveSum(dd * dd);
  if ((t & 63) == 0) scr[t >> 6] = v;
  __syncthreads();
  float rstd = rsqrtf((scr[0] + scr[1]) * (1.f / 128.f) + 1e-5f);
  mx1[(size_t)rg * 128 + t] = dd * rstd * g[t] + bt[t];
}

// ---------------- K5 (fat-block MFMA, 64-row chunks, 2 blocks/CU): per (b,h,irow) [r13 proven] ----------------
__global__ __launch_bounds__(512, 4) void k5_row(
    const float* __restrict__ prot_adj,
    const u16* __restrict__ msg_hi, const u16* __restrict__ msg_lo,
    const u16* __restrict__ wk_hi,   // fragment layout; lo at +16384
    const u16* __restrict__ wo_hi,   // fragment layout; lo at +16384
    const float* __restrict__ bk, const float* __restrict__ bo,
    const float* __restrict__ g1, const float* __restrict__ b1,
    const float* __restrict__ g4, const float* __restrict__ b4,
    float* __restrict__ rs128) {
  __shared__ __align__(16) unsigned char Lmem[72704];
  float (*paF)[132] = (float(*)[132])Lmem;                       // 64x132 f32 = 33792 B
  u16* kBh = (u16*)(Lmem + 33792);                               // 32x264 u16 = 16896 B
  u16* kBl = (u16*)(Lmem + 33792 + 16896);                       // 16896 B
  float (*e2)[132] = (float(*)[132])(Lmem + 33792);              // overlay on kB (33792 B)
  float* psum  = (float*)(Lmem + 67584);                         // 512 f
  float* meanL = (float*)(Lmem + 69632);                         // 64 f
  float* rstdL = (float*)(Lmem + 69888);                         // 64 f
  float* accL  = (float*)(Lmem + 70144);                         // 128 f
  float* scr2  = (float*)(Lmem + 70656);                         // 512 f (ends 72704)
  int t = threadIdx.x;
  int bid = (blockIdx.x & 7) * 256 + (blockIdx.x >> 3);
  int b = bid >> 8, h = (bid >> 5) & 7, irow_rel = bid & 31;
  int irow = h * 32 + irow_rel;
  int w = t >> 6, l = t & 63;
  const int lr = l & 15, lk = l >> 4;
  const int wr = w & 3, wq = w >> 2;       // row-quarter / q-half for P3, P6
  const size_t mb = ((size_t)(b * 8 + h)) << 16;
  if (t < 128) accL[t] = 0.f;
  for (int chunk = 0; chunk < 2; chunk++) {
    __syncthreads();
    // P1: load 128 pa vectors in two 64-row halves? No: 2 chunks of 128 columns handled as
    // r13: chunk covers cols chunk*128.. in two 64-row LDS passes -> here: 4 sub-chunks of 64.
    // (kept identical to r13: loop below does 64 pa vectors per iteration, 4 iterations total)
    __syncthreads();
  }
  // r13 structure: 4 chunks of 64 pa vectors
  for (int chunk = 0; chunk < 4; chunk++) {
    __syncthreads();
    {
      size_t pabase = (((size_t)(b * 256) + irow) * 256 + chunk * 64) * 128;
      const float4* src4 = (const float4*)(prot_adj + pabase);
      for (int idx = t; idx < 2048; idx += 512)
        *(float4*)&paF[idx >> 5][(idx & 31) * 4] = src4[idx];
    }
    __syncthreads();
    ln64_stats(paF, psum, meanL, rstdL, t);
    for (int idx = t; idx < 8192; idx += 512) {
      int r = idx >> 7, c = idx & 127;
      paF[r][c] = (paF[r][c] - meanL[r]) * rstdL[r] * g1[c] + b1[c];
    }
    __syncthreads();
    // P3: Lin_k [64 rows x 128 o]: wave w -> rows wr*16.., q = wq*4 + 0..3
    {
      f32x4 acc1[4];
#pragma unroll
      for (int qq = 0; qq < 4; qq++) acc1[qq] = (f32x4){0.f, 0.f, 0.f, 0.f};
#pragma unroll 1
      for (int kk = 0; kk < 4; kk++) {
        bf16x8 ah, al;
        split8(&paF[wr * 16 + lr][kk * 32 + lk * 8], ah, al);
#pragma unroll
        for (int qq = 0; qq < 4; qq++) {
          int q = wq * 4 + qq;
          bf16x8 bh = *(const bf16x8*)&wk_hi[q * 2048 + kk * 512 + l * 8];
          bf16x8 bl = *(const bf16x8*)&wk_hi[16384 + q * 2048 + kk * 512 + l * 8];
          acc1[qq] = MFMA(ah, bh, acc1[qq]);
          acc1[qq] = MFMA(al, bh, acc1[qq]);
          acc1[qq] = MFMA(ah, bl, acc1[qq]);
        }
      }
#pragma unroll
      for (int qq = 0; qq < 4; qq++) {
        int q = wq * 4 + qq;
        float bkv = bk[q * 16 + lr];
#pragma unroll
        for (int j = 0; j < 4; j++) {
          int rloc = wr * 16 + lk * 4 + j;
          int n = (rloc & 31) * 8 + q;
          int colB = (rloc >> 5) * 16 + lr;
          u16 hh, ll; split1(acc1[qq][j] + bkv, hh, ll);
          kBh[colB * 264 + n] = hh; kBl[colB * 264 + n] = ll;
        }
      }
    }
    __syncthreads();
    // P4: E-GEMM [256m x 32col] = msg[256x256] @ kB ; wave w -> m in [w*32, +32)
    f32x4 eacc[2][2];
#pragma unroll
    for (int mt = 0; mt < 2; mt++)
#pragma unroll
      for (int ct = 0; ct < 2; ct++) eacc[mt][ct] = (f32x4){0.f, 0.f, 0.f, 0.f};
#pragma unroll 1
    for (int kk = 0; kk < 8; kk++) {
      bf16x8 bhv[2], blv[2];
#pragma unroll
      for (int ct = 0; ct < 2; ct++) {
        bhv[ct] = *(const bf16x8*)&kBh[(ct * 16 + lr) * 264 + kk * 32 + lk * 8];
        blv[ct] = *(const bf16x8*)&kBl[(ct * 16 + lr) * 264 + kk * 32 + lk * 8];
      }
#pragma unroll
      for (int mt = 0; mt < 2; mt++) {
        size_t ro = mb + (size_t)((w * 2 + mt) * 4096 + kk * 512 + l * 8);
        bf16x8 ah = *(const bf16x8*)&msg_hi[ro];
        bf16x8 al = *(const bf16x8*)&msg_lo[ro];
#pragma unroll
        for (int ct = 0; ct < 2; ct++) {
          eacc[mt][ct] = MFMA(ah, bhv[ct], eacc[mt][ct]);
          eacc[mt][ct] = MFMA(al, bhv[ct], eacc[mt][ct]);
          eacc[mt][ct] = MFMA(ah, blv[ct], eacc[mt][ct]);
        }
      }
    }
    __syncthreads();  // all waves done reading kB before e2 overlay write
    // P5: scatter E -> e2[(colE>>4)*32 + (m>>3)][(m&7)*16 + (colE&15)]
#pragma unroll
    for (int mt = 0; mt < 2; mt++)
#pragma unroll
      for (int ct = 0; ct < 2; ct++)
#pragma unroll
        for (int j = 0; j < 4; j++) {
          int m = w * 32 + mt * 16 + lk * 4 + j;
          int colE = ct * 16 + lr;
          e2[(colE >> 4) * 32 + (m >> 3)][(m & 7) * 16 + (colE & 15)] = eacc[mt][ct][j];
        }
    __syncthreads();
    // P6: Lin_out [64 rows x 128 o] + residual into paF: wave w -> rows wr*16, q = wq*4+qq
    {
      f32x4 oacc[4];
#pragma unroll
      for (int qq = 0; qq < 4; qq++) oacc[qq] = (f32x4){0.f, 0.f, 0.f, 0.f};
#pragma unroll 1
      for (int kk = 0; kk < 4; kk++) {
        bf16x8 ah, al;
        split8(&e2[wr * 16 + lr][kk * 32 + lk * 8], ah, al);
#pragma unroll
        for (int qq = 0; qq < 4; qq++) {
          int q = wq * 4 + qq;
          bf16x8 bh = *(const bf16x8*)&wo_hi[q * 2048 + kk * 512 + l * 8];
          bf16x8 bl = *(const bf16x8*)&wo_hi[16384 + q * 2048 + kk * 512 + l * 8];
          oacc[qq] = MFMA(ah, bh, oacc[qq]);
          oacc[qq] = MFMA(al, bh, oacc[qq]);
          oacc[qq] = MFMA(ah, bl, oacc[qq]);
        }
      }
      __syncthreads();
#pragma unroll
      for (int qq = 0; qq < 4; qq++) {
        int o = (wq * 4 + qq) * 16 + lr;
        float bv = bo[o];
#pragma unroll
        for (int j = 0; j < 4; j++) {
          int rloc = wr * 16 + lk * 4 + j;
          paF[rloc][o] = oacc[qq][j] + bv + paF[rloc][o];
        }
      }
    }
    __syncthreads();
    // P7: LN over 64 result rows, column partial reduce into accL
    ln64_stats(paF, psum, meanL, rstdL, t);
    {
      int c = t & 127, rh = t >> 7;
      float part = 0;
#pragma unroll
      for (int rr = 0; rr < 16; rr++) {
        int r2 = rh * 16 + rr;
        part += (paF[r2][c] - meanL[r2]) * rstdL[r2];
      }
      scr2[rh * 128 + c] = part;
    }
    __syncthreads();
    if (t < 128) accL[t] += scr2[t] + scr2[128 + t] + scr2[256 + t] + scr2[384 + t];
  }
  __syncthreads();
  if (t < 128)
    atomicAdd(&rs128[(b * 8 + h) * 128 + t], g4[t] * accL[t] + 256.f * b4[t]);
}

// ---------------- ksum from rowsum128 ----------------
__global__ __launch_bounds__(128) void ksum_kernel(const float* __restrict__ rs128, const float* __restrict__ WT,
                                                   const float* __restrict__ bias, float* __restrict__ ks) {
  int bh = blockIdx.x, t = threadIdx.x;
  __shared__ float rsL[128];
  __shared__ float pcL[128];
  rsL[t] = rs128[bh * 128 + t];
  __syncthreads();
  float pc = 0;
#pragma unroll 8
  for (int i = 0; i < 128; i++) pc += rsL[i] * WT[i * 128 + t];
  pcL[t] = pc;
  __syncthreads();
  if (t < 16) {
    float kv = 0;
    for (int g8 = 0; g8 < 8; g8++) kv += pcL[g8 * 16 + t] + 8192.f * bias[g8 * 16 + t];
    ks[bh * 16 + t] = kv;
  }
}

// ---------------- se + vasum from ma rows ----------------
__global__ __launch_bounds__(256) void se_vasum(
    const float* __restrict__ ma, const float* __restrict__ WTqa, const float* __restrict__ bqa,
    const float* __restrict__ WTva, const float* __restrict__ bva,
    const float* __restrict__ ks, float* __restrict__ se, float* __restrict__ vas) {
  __shared__ __align__(16) float w[16384];
  __shared__ float rows[16 * 129];
  __shared__ float red[4096];
  int t = threadIdx.x, bid = blockIdx.x;
  int b = bid >> 8, iq = (bid >> 2) & 63, jb = bid & 3, j0 = jb * 16;
  int h = iq >> 3;
  float ksumv[16];
#pragma unroll
  for (int d = 0; d < 16; d++) ksumv[d] = ks[(b * 8 + h) * 16 + d];
  size_t rowbase = ((size_t)(b * 64 + iq) * 64 + j0) * 128;
  for (int idx = t; idx < 2048; idx += 256) rows[(idx >> 7) * 129 + (idx & 127)] = ma[rowbase + idx];
  for (int idx = t; idx < 16384; idx += 256) w[idx] = WTqa[idx];
  __syncthreads();
  int g8 = t >> 5, r = (t >> 1) & 15, iseg = t & 1;
  {
    float acc[16];
#pragma unroll
    for (int d = 0; d < 16; d++) acc[d] = 0.f;
    for (int ii = 0; ii < 64; ii++) {
      int i2 = iseg * 64 + ii;
      float pav = rows[r * 129 + i2];
      float wv[16];
      const float4* w4 = (const float4*)&w[i2 * 128 + g8 * 16];
      *(float4*)&wv[0] = w4[0]; *(float4*)&wv[4] = w4[1]; *(float4*)&wv[8] = w4[2]; *(float4*)&wv[12] = w4[3];
#pragma unroll
      for (int d = 0; d < 16; d++) acc[d] += pav * wv[d];
    }
    float sval = 0;
#pragma unroll
    for (int d = 0; d < 16; d++) sval += acc[d] * ksumv[d];
    red[(r * 8 + g8) * 2 + iseg] = sval;
    __syncthreads();
    if (t < 128) {
      int rr = t >> 3, gg = t & 7;
      float sv = red[(rr * 8 + gg) * 2] + red[(rr * 8 + gg) * 2 + 1];
      float bdot = 0;
#pragma unroll
      for (int d = 0; d < 16; d++) bdot += bqa[gg * 16 + d] * ksumv[d];
      sv += bdot;
      int jj = j0 + rr;
      int mm = (iq & 7) * 8 + (jj >> 3);
      int n2 = (jj & 7) * 8 + gg;
      se[((size_t)(b * 8 + h) * 64 + mm) * 64 + n2] = INV_SCALE * sv;
    }
    __syncthreads();
  }
  for (int idx = t; idx < 16384; idx += 256) w[idx] = WTva[idx];
  __syncthreads();
  {
    float acc[16];
#pragma unroll
    for (int d = 0; d < 16; d++) acc[d] = 0.f;
    for (int ii = 0; ii < 64; ii++) {
      int i2 = iseg * 64 + ii;
      float pav = rows[r * 129 + i2];
      float wv[16];
      const float4* w4 = (const float4*)&w[i2 * 128 + g8 * 16];
      *(float4*)&wv[0] = w4[0]; *(float4*)&wv[4] = w4[1]; *(float4*)&wv[8] = w4[2]; *(float4*)&wv[12] = w4[3];
#pragma unroll
      for (int d = 0; d < 16; d++) acc[d] += pav * wv[d];
    }
    if (iseg == 0) {
#pragma unroll
      for (int d = 0; d < 16; d++) acc[d] += bva[g8 * 16 + d];
    }
#pragma unroll
    for (int d = 0; d < 16; d++) red[t * 16 + d] = acc[d];
    __syncthreads();
    if (t < 32) {
      int mgrp = t >> 4, d = t & 15;
      float sm = 0;
      for (int gg = 0; gg < 8; gg++)
        for (int rr = mgrp * 8; rr < mgrp * 8 + 8; rr++) {
          sm += red[(gg * 32 + rr * 2) * 16 + d] + red[(gg * 32 + rr * 2 + 1) * 16 + d];
        }
      int mv = (iq & 7) * 8 + jb * 2 + mgrp;
      atomicAdd(&vas[((size_t)(b * 8 + h) * 64 + mv) * 16 + d], sm);
    }
  }
}

// ---------------- me2 from se ----------------
__global__ __launch_bounds__(256) void me2_kernel(const float* __restrict__ se, float* __restrict__ me2) {
  __shared__ float sL[64 * 65];
  __shared__ float rmaxL[64], rsinv[64], cmaxL[64], csinv[64];
  int bh = blockIdx.x, t = threadIdx.x;
  for (int idx = t; idx < 4096; idx += 256) sL[(idx >> 6) * 65 + (idx & 63)] = se[(size_t)bh * 4096 + idx];
  __syncthreads();
  if (t < 64) {
    float mx = -3.4e38f;
    for (int n = 0; n < 64; n++) mx = fmaxf(mx, sL[t * 65 + n]);
    float sm = 0;
    for (int n = 0; n < 64; n++) sm += __expf(sL[t * 65 + n] - mx);
    rmaxL[t] = mx; rsinv[t] = 1.f / sm;
  } else if (t < 128) {
    int n = t - 64;
    float mx = -3.4e38f;
    for (int m = 0; m < 64; m++) mx = fmaxf(mx, sL[m * 65 + n]);
    float sm = 0;
    for (int m = 0; m < 64; m++) sm += __expf(sL[m * 65 + n] - mx);
    cmaxL[n] = mx; csinv[n] = 1.f / sm;
  }
  __syncthreads();
  for (int idx = t; idx < 4096; idx += 256) {
    int m = idx >> 6, n = idx & 63;
    float x = sL[m * 65 + n];
    me2[(size_t)bh * 4096 + idx] = __expf(x - rmaxL[m]) * rsinv[m] + __expf(x - cmaxL[n]) * csinv[n];
  }
}

// ---------------- ma1 = LN(ma + Lin(me2*vasum rows)) ----------------
__global__ __launch_bounds__(256) void ma1_kernel(
    const float* __restrict__ ma, const float* __restrict__ me2, const float* __restrict__ vas,
    const float* __restrict__ WT, const float* __restrict__ bias,
    const float* __restrict__ g, const float* __restrict__ bt, float* __restrict__ ma1) {
  __shared__ __align__(16) float w[16384];
  __shared__ float rows[16 * 129];
  __shared__ float ored[4096];
  __shared__ float psum[256];
  __shared__ float meanL[16], rstdL[16];
  int t = threadIdx.x, bid = blockIdx.x;
  int b = bid >> 8, iq = (bid >> 2) & 63, jb = bid & 3, j0 = jb * 16;
  int h = iq >> 3;
  int bh64 = (b * 8 + h) * 64;
  size_t rowbase = ((size_t)(b * 64 + iq) * 64 + j0) * 128;
  for (int idx = t; idx < 2048; idx += 256) {
    int r = idx >> 7, c = idx & 127;
    int mm = (iq & 7) * 8 + jb * 2 + (r >> 3);
    int nn = (r & 7) * 8 + (c >> 4);
    rows[r * 129 + c] = me2[(size_t)(bh64 + mm) * 64 + nn] * vas[(size_t)(bh64 + mm) * 16 + (c & 15)];
  }
  for (int idx = t; idx < 16384; idx += 256) w[idx] = WT[idx];
  __syncthreads();
  int g8 = t >> 5, r = (t >> 1) & 15, iseg = t & 1;
  {
    float acc[16];
#pragma unroll
    for (int d = 0; d < 16; d++) acc[d] = 0.f;
    for (int ii = 0; ii < 64; ii++) {
      int i2 = iseg * 64 + ii;
      float pav = rows[r * 129 + i2];
      float wv[16];
      const float4* w4 = (const float4*)&w[i2 * 128 + g8 * 16];
      *(float4*)&wv[0] = w4[0]; *(float4*)&wv[4] = w4[1]; *(float4*)&wv[8] = w4[2]; *(float4*)&wv[12] = w4[3];
#pragma unroll
      for (int d = 0; d < 16; d++) acc[d] += pav * wv[d];
    }
    float* od = &ored[(iseg * 16 + r) * 128 + g8 * 16];
#pragma unroll
    for (int d = 0; d < 16; d++) od[d] = acc[d];
  }
  __syncthreads();
  for (int idx = t; idx < 2048; idx += 256) {
    int r2 = idx >> 7, c = idx & 127;
    rows[r2 * 129 + c] = ored[r2 * 128 + c] + ored[(16 + r2) * 128 + c] + bias[c] + ma[rowbase + idx];
  }
  __syncthreads();
  {
    int rr = t >> 4, seg = t & 15;
    float p = 0;
#pragma unroll
    for (int k = 0; k < 8; k++) p += rows[rr * 129 + seg * 8 + k];
    psum[rr * 16 + seg] = p;
    __syncthreads();
    if (t < 16) { float sm = 0; for (int k = 0; k < 16; k++) sm += psum[t * 16 + k]; meanL[t] = sm * (1.f / 128.f); }
    __syncthreads();
    float mu = meanL[rr];
    p = 0;
#pragma unroll
    for (int k = 0; k < 8; k++) { float d = rows[rr * 129 + seg * 8 + k] - mu; p += d * d; }
    psum[rr * 16 + seg] = p;
    __syncthreads();
    if (t < 16) { float sm = 0; for (int k = 0; k < 16; k++) sm += psum[t * 16 + k]; rstdL[t] = rsqrtf(sm * (1.f / 128.f) + 1e-5f); }
    __syncthreads();
  }
  for (int idx = t; idx < 2048; idx += 256) {
    int r2 = idx >> 7, c = idx & 127;
    ma1[rowbase + idx] = (rows[r2 * 129 + c] - meanL[r2]) * rstdL[r2] * g[c] + bt[c];
  }
}

// ---------------- MLP (pure-bf16 RNE MFMA, fragment weights) + residual + final LN ----------------
__global__ __launch_bounds__(256, 4) void mlp_mfma(
    const float* __restrict__ in,
    const u16* __restrict__ w1h,   // fragment [32q][4kk][64][8] RNE bf16
    const float* __restrict__ b1,
    const u16* __restrict__ w2h,   // fragment [8q][16kk][64][8] RNE bf16
    const float* __restrict__ b2,
    const float* __restrict__ g, const float* __restrict__ bt, float* __restrict__ out) {
  __shared__ __align__(16) float rowL[16][132];
  __shared__ __align__(16) u16 hh[16][520];
  __shared__ float psum[256];
  __shared__ float meanL[16], rstdL[16];
  int t = threadIdx.x, bid = blockIdx.x;
  int w = t >> 6, l = t & 63, lr = l & 15, lk = l >> 4;
  size_t base = (size_t)bid * 2048;
  {
    const float4* src4 = (const float4*)(in + base);
    for (int idx = t; idx < 512; idx += 256)
      *(float4*)&rowL[idx >> 5][(idx & 31) * 4] = src4[idx];
  }
  __syncthreads();
  {
    f32x4 acc1[8];
#pragma unroll
    for (int nt = 0; nt < 8; nt++) acc1[nt] = (f32x4){0.f, 0.f, 0.f, 0.f};
#pragma unroll 1
    for (int kk = 0; kk < 4; kk++) {
      bf16x8 ah = rne8(&rowL[lr][kk * 32 + lk * 8]);
#pragma unroll
      for (int nt = 0; nt < 8; nt++) {
        int q = w * 8 + nt;
        bf16x8 bh = *(const bf16x8*)&w1h[q * 2048 + kk * 512 + l * 8];
        acc1[nt] = MFMA(ah, bh, acc1[nt]);
      }
    }
#pragma unroll
    for (int nt = 0; nt < 8; nt++) {
      int o = w * 128 + nt * 16 + lr;
      float bb = b1[o];
#pragma unroll
      for (int j = 0; j < 4; j++) {
        int m = lk * 4 + j;
        float hv = 1.f / (1.f + __expf(-(acc1[nt][j] + bb)));
        hh[m][o] = rne1(hv);
      }
    }
  }
  __syncthreads();
  {
    f32x4 acc2[2];
#pragma unroll
    for (int nt = 0; nt < 2; nt++) acc2[nt] = (f32x4){0.f, 0.f, 0.f, 0.f};
#pragma unroll 1
    for (int kk = 0; kk < 16; kk++) {
      bf16x8 ah = *(const bf16x8*)&hh[lr][kk * 32 + lk * 8];
#pragma unroll
      for (int nt = 0; nt < 2; nt++) {
        int q = w * 2 + nt;
        bf16x8 bh = *(const bf16x8*)&w2h[q * 8192 + kk * 512 + l * 8];
        acc2[nt] = MFMA(ah, bh, acc2[nt]);
      }
    }
    __syncthreads();
#pragma unroll
    for (int nt = 0; nt < 2; nt++) {
      int c = w * 32 + nt * 16 + lr;
      float bb = b2[c];
#pragma unroll
      for (int j = 0; j < 4; j++) {
        int m = lk * 4 + j;
        rowL[m][c] = acc2[nt][j] + bb + rowL[m][c];
      }
    }
  }
  __syncthreads();
  {
    int rr = t >> 4, seg = t & 15;
    float p = 0;
#pragma unroll
    for (int k = 0; k < 8; k++) p += rowL[rr][seg * 8 + k];
    psum[rr * 16 + seg] = p;
    __syncthreads();
    if (t < 16) { float sm = 0; for (int k = 0; k < 16; k++) sm += psum[t * 16 + k]; meanL[t] = sm * (1.f / 128.f); }
    __syncthreads();
    float mu = meanL[rr];
    p = 0;
#pragma unroll
    for (int k = 0; k < 8; k++) { float d = rowL[rr][seg * 8 + k] - mu; p += d * d; }
    psum[rr * 16 + seg] = p;
    __syncthreads();
    if (t < 16) { float sm = 0; for (int k = 0; k < 16; k++) sm += psum[t * 16 + k]; rstdL[t] = rsqrtf(sm * (1.f / 128.f) + 1e-5f); }
    __syncthreads();
  }
  for (int idx = t; idx < 2048; idx += 256) {
    int r2 = idx >> 7, cc = idx & 127;
    out[base + idx] = (rowL[r2][cc] - meanL[r2]) * rstdL[r2] * g[cc] + bt[cc];
  }
}

extern "C" void kernel_launch(void* const* d_in, const int* in_sizes, int n_in,
                              void* d_out, int out_size, void* d_ws, size_t ws_size,
                              hipStream_t stream) {
  (void)in_sizes; (void)n_in; (void)out_size; (void)ws_size;
  const float* mol_annot  = (const float*)d_in[0];
  const float* prot_annot = (const float*)d_in[1];
  const float* mol_adj    = (const float*)d_in[2];
  const float* prot_adj   = (const float*)d_in[3];
  const float* att_w = (const float*)d_in[4];
  const float* att_b = (const float*)d_in[5];
  const float* dec_w = (const float*)d_in[6];
  const float* dec_b = (const float*)d_in[7];
  const float* mlp_w1 = (const float*)d_in[8];
  const float* mlp_b1 = (const float*)d_in[9];
  const float* mlp_w2 = (const float*)d_in[10];
  const float* mlp_b2 = (const float*)d_in[11];
  const float* ln_g = (const float*)d_in[12];
  const float* ln_b = (const float*)d_in[13];
  float* out = (float*)d_out;
  float* ws = (float*)d_ws;

  const u16* wk_hi = (const u16*)(ws + WT_ATT + 16384);
  const u16* wo_hi = (const u16*)(ws + WT_ATT + 3 * 16384);
  u16* msg_hi = (u16*)(ws + O_MA1);          // O_MA1 region free until ma1_kernel
  u16* msg_lo = msg_hi + 4194304;
  float* pmaxp = ws + O_MSG;                 // O_MSG region free (msg f32 eliminated)
  float* psump = ws + O_MSG + 131072;

  hipMemsetAsync(ws + O_RS, 0, 8192 * sizeof(float), stream);
  hipMemsetAsync(ws + O_VAS, 0, 65536 * sizeof(float), stream);
  prep_wt<<<17, 256, 0, stream>>>(att_w, dec_w, mlp_w1, mlp_w2, ws);
  ln_rows4<<<512, 128, 0, stream>>>(prot_annot, ws + O_PX, ln_g + 384, ln_b + 384);
  ln_rows4<<<128, 128, 0, stream>>>(mol_annot, ws + O_MX, ln_g + 256, ln_b + 256);
  ln_rows4<<<8192, 128, 0, stream>>>(mol_adj, ws + O_MA, ln_g, ln_b);
  lin_rows2<<<2048, 128, 0, stream>>>(ws + O_PX, ws + O_QL, ws + WT_ATT, att_b,
                                      ws + O_VL, ws + WT_ATT + 2 * 16384, att_b + 256);
  lin_rows2<<<512, 128, 0, stream>>>(ws + O_MX, ws + O_QXL, ws + WT_DEC, dec_b,
                                     ws + O_VXL, ws + WT_DEC + 2 * 16384, dec_b + 256);
  k1_fold<<<16384, 256, 0, stream>>>(prot_adj, ws + O_QL, att_w + 16384, att_b + 128,
                                     ln_g + 128, ln_b + 128, ws + O_S);
  col_part<<<512, 256, 0, stream>>>(ws + O_S, pmaxp, psump);
  msg_tiles<<<512, 256, 0, stream>>>(ws + O_S, pmaxp, psump, ws + O_VL, msg_hi, msg_lo, ws + O_NH);
  px1k_kernel<<<2048, 128, 0, stream>>>(ws + O_PX, ws + O_NH, ws + WT_ATT + 4 * 16384, att_b + 512,
                                        ln_g + 640, ln_b + 640, ws + WT_DEC + 16384, dec_b + 128,
                                        ws + O_KXL);
  s2_fused<<<64, 512, 0, stream>>>(ws + O_QXL, ws + O_KXL, out + OUT2_OFF, ws + O_MROW);
  mx1_kernel<<<512, 128, 0, stream>>>(ws + O_MX, ws + O_MROW, ws + O_VXL, ws + WT_DEC + 6 * 16384,
                                      dec_b + 768, ln_g + 896, ln_b + 896, ws + O_MX1);
  k5_row<<<2048, 512, 0, stream>>>(prot_adj, msg_hi, msg_lo, wk_hi, wo_hi,
                                   att_b + 128, att_b + 384,
                                   ln_g + 128, ln_b + 128, ln_g + 512, ln_b + 512, ws + O_RS);
  ksum_kernel<<<64, 128, 0, stream>>>(ws + O_RS, ws + WT_DEC + 4 * 16384, dec_b + 512, ws + O_KS);
  se_vasum<<<2048, 256, 0, stream>>>(ws + O_MA, ws + WT_DEC + 3 * 16384, dec_b + 384,
                                     ws + WT_DEC + 5 * 16384, dec_b + 640, ws + O_KS, ws + O_SE, ws + O_VAS);
  me2_kernel<<<64, 256, 0, stream>>>(ws + O_SE, ws + O_ME2);
  ma1_kernel<<<2048, 256, 0, stream>>>(ws + O_MA, ws + O_ME2, ws + O_VAS, ws + WT_DEC + 7 * 16384,
                                       dec_b + 896, ln_g + 768, ln_b + 768, ws + O_MA1);
  mlp_mfma<<<2048, 256, 0, stream>>>(ws + O_MA1, (const u16*)(ws + WT_M1), mlp_b1,
                                     (const u16*)(ws + WT_M2), mlp_b2,
                                     ln_g + 1024, ln_b + 1024, out);
  mlp_mfma<<<32, 256, 0, stream>>>(ws + O_MX1, (const u16*)(ws + WT_M1 + 65536), mlp_b1 + 512,
                                   (const u16*)(ws + WT_M2 + 65536), mlp_b2 + 128,
                                   ln_g + 1152, ln_b + 1152, out + OUT1_OFF);
}